// Round 6
// baseline (1360.963 us; speedup 1.0000x reference)
//
#include <hip/hip_runtime.h>
#include <hip/hip_bf16.h>
#include <math.h>

#define NNODES 20000
#define NPAD   20480   // 160 * 128 (160 bm strips -> 20 per XCD)
#define NBM    160
#define NEDGES 320000
#define HEADS  4
#define DDIM   256
#define MCOLS  1024   // H*D

typedef __attribute__((ext_vector_type(8))) short short8;
typedef __attribute__((ext_vector_type(4))) float f32x4;

// bf16 helpers (bit-level, RNE)
__device__ __forceinline__ unsigned short f2bf(float f) {
  unsigned u = __float_as_uint(f);
  unsigned r = (u + 0x7fffu + ((u >> 16) & 1u)) >> 16;
  return (unsigned short)r;
}
__device__ __forceinline__ float bf2f(unsigned short h) {
  return __uint_as_float(((unsigned)h) << 16);
}
// unpack packed bf16 pair from a uint
__device__ __forceinline__ float blo(unsigned v) { return __uint_as_float(v << 16); }
__device__ __forceinline__ float bhi(unsigned v) { return __uint_as_float(v & 0xffff0000u); }

__device__ __forceinline__ void async_ld16(void* lds, const void* g) {
  __builtin_amdgcn_global_load_lds(
      (const __attribute__((address_space(1))) unsigned int*)g,
      (__attribute__((address_space(3))) unsigned int*)lds, 16, 0, 0);
}

// ---------------- CSR build (by dst) ----------------
__global__ void k_zero(int* deg, int n) {
  int i = blockIdx.x*blockDim.x + threadIdx.x;
  if (i < n) deg[i] = 0;
}
__global__ void k_hist(const int* __restrict__ dst, int* deg, int e) {
  int i = blockIdx.x*blockDim.x + threadIdx.x;
  if (i < e) atomicAdd(&deg[dst[i]], 1);
}
__global__ void k_scan(const int* __restrict__ deg, int* row_ptr, int* cursor) {
  __shared__ int sm[1024];
  int t = threadIdx.x;
  const int CH = 20;
  int base = t*CH;
  int s = 0;
  #pragma unroll
  for (int i = 0; i < CH; ++i) { int idx = base+i; if (idx < NNODES) s += deg[idx]; }
  int val = s;
  sm[t] = s; __syncthreads();
  for (int off = 1; off < 1024; off <<= 1) {
    int add = (t >= off) ? sm[t-off] : 0;
    __syncthreads();
    val += add; sm[t] = val;
    __syncthreads();
  }
  int run = val - s;
  for (int i = 0; i < CH; ++i) {
    int idx = base+i;
    if (idx < NNODES) { row_ptr[idx] = run; cursor[idx] = run; run += deg[idx]; }
  }
  if (t == 0) row_ptr[NNODES] = NEDGES;
}
__global__ void k_fill(const int* __restrict__ src, const int* __restrict__ dst,
                       int* cursor, int* srcs_sorted, int* dsts_sorted, int e) {
  int i = blockIdx.x*blockDim.x + threadIdx.x;
  if (i < e) {
    int d = dst[i];
    int pos = atomicAdd(&cursor[d], 1);
    srcs_sorted[pos] = src[i];
    dsts_sorted[pos] = d;
  }
}

// ---------------- all six folds in one launch ----------------
__device__ __forceinline__ void fold_body(const float* __restrict__ W,
                                          const float* __restrict__ v,
                                          float* __restrict__ F, int K, int bb) {
  int wave = threadIdx.x >> 6, lane = threadIdx.x & 63;
  int p = bb*4 + wave;            // p < K*4
  int k = p >> 2, h = p & 3;
  const float4 wv = *(const float4*)&W[(size_t)k*MCOLS + h*DDIM + lane*4];
  const float4 av = *(const float4*)&v[h*DDIM + lane*4];
  float s = wv.x*av.x + wv.y*av.y + wv.z*av.z + wv.w*av.w;
  for (int off = 32; off; off >>= 1) s += __shfl_xor(s, off);
  if (lane == 0) F[k*HEADS + h] = s;
}
__global__ __launch_bounds__(256) void k_fold_all(
    const float* Wd0, const float* ar0, float* F0,
    const float* Ws0, const float* al0, float* G0,
    const float* Wd1, const float* ar1, float* F1,
    const float* Ws1, const float* al1, float* G1,
    const float* Wd2, const float* ar2, float* F2,
    const float* Ws2, const float* al2, float* G2) {
  int b = blockIdx.x;
  if      (b < 512)  fold_body(Wd0, ar0, F0, 512,  b);
  else if (b < 1024) fold_body(Ws0, al0, G0, 512,  b - 512);
  else if (b < 2048) fold_body(Wd1, ar1, F1, 1024, b - 1024);
  else if (b < 3072) fold_body(Ws1, al1, G1, 1024, b - 2048);
  else if (b < 4096) fold_body(Wd2, ar2, F2, 1024, b - 3072);
  else               fold_body(Ws2, al2, G2, 1024, b - 4096);
}

// ---------------- layer-0 prep: split-bf16 A + el0/er0, one pass over x ----------
__global__ __launch_bounds__(256) void k_prep0(
    const float* __restrict__ x, const float* __restrict__ Wal,
    const float* __restrict__ Wred,
    unsigned short* __restrict__ hi, unsigned short* __restrict__ lo,
    float* __restrict__ el, float* __restrict__ er) {
  __shared__ float red_sm[4][8];
  int n = blockIdx.x, t = threadIdx.x;
  if (n >= NNODES) {
    *(ushort2*)&hi[(size_t)n*512 + 2*t] = (ushort2){0,0};
    *(ushort2*)&lo[(size_t)n*512 + 2*t] = (ushort2){0,0};
    return;
  }
  float2 xv = *(const float2*)&x[(size_t)n*512 + 2*t];
  ushort2 h2, l2;
  h2.x = f2bf(xv.x); l2.x = f2bf(xv.x - bf2f(h2.x));
  h2.y = f2bf(xv.y); l2.y = f2bf(xv.y - bf2f(h2.y));
  *(ushort2*)&hi[(size_t)n*512 + 2*t] = h2;
  *(ushort2*)&lo[(size_t)n*512 + 2*t] = l2;
  const float4 wa0 = *(const float4*)&Wal[(2*t)*4];
  const float4 wa1 = *(const float4*)&Wal[(2*t+1)*4];
  const float4 wr0 = *(const float4*)&Wred[(2*t)*4];
  const float4 wr1 = *(const float4*)&Wred[(2*t+1)*4];
  float p[8];
  p[0] = xv.x*wa0.x + xv.y*wa1.x;
  p[1] = xv.x*wa0.y + xv.y*wa1.y;
  p[2] = xv.x*wa0.z + xv.y*wa1.z;
  p[3] = xv.x*wa0.w + xv.y*wa1.w;
  p[4] = xv.x*wr0.x + xv.y*wr1.x;
  p[5] = xv.x*wr0.y + xv.y*wr1.y;
  p[6] = xv.x*wr0.z + xv.y*wr1.z;
  p[7] = xv.x*wr0.w + xv.y*wr1.w;
  for (int off = 32; off; off >>= 1)
    #pragma unroll
    for (int j = 0; j < 8; ++j) p[j] += __shfl_xor(p[j], off);
  if ((t & 63) == 0)
    #pragma unroll
    for (int j = 0; j < 8; ++j) red_sm[t >> 6][j] = p[j];
  __syncthreads();
  if (t < 8) {
    float v = (red_sm[0][t] + red_sm[1][t]) + (red_sm[2][t] + red_sm[3][t]);
    if (t < 4) el[n*HEADS + t] = v;
    else       er[n*HEADS + (t-4)] = v;
  }
}

// ---------------- combined: W transpose->bf16 + per-edge softmax weights ----------
// wb layout is HEAD-MAJOR: wb[h*NEDGES + pos] (so slice-agg reads a contiguous
// per-head column instead of pulling all 4 heads' lines into L2).
__global__ __launch_bounds__(256) void k_cvtw_wgt(
    const float* __restrict__ W, unsigned short* __restrict__ Th, int K,
    const float* __restrict__ el, const float* __restrict__ er,
    const int* __restrict__ srcs, const int* __restrict__ dsts,
    float* __restrict__ wb, int e4) {
  int b = blockIdx.x;
  if (b < K) {   // transpose part: K blocks (32 n-tiles x K/32 k-tiles)
    __shared__ float sm[32][33];
    int n0 = (b & 31)*32, k0 = (b >> 5)*32;
    int t = threadIdx.x;
    int r = t >> 3, c4 = (t & 7)*4;
    *(float4*)&sm[r][c4] = *(const float4*)&W[(size_t)(k0 + r)*MCOLS + n0 + c4];
    __syncthreads();
    ushort4 h;
    h.x = f2bf(sm[c4+0][r]);
    h.y = f2bf(sm[c4+1][r]);
    h.z = f2bf(sm[c4+2][r]);
    h.w = f2bf(sm[c4+3][r]);
    *(ushort4*)&Th[(size_t)(n0 + r)*K + k0 + c4] = h;
  } else {
    int i = (b - K)*256 + threadIdx.x;
    if (i < e4) {
      int h = i / NEDGES;          // head plane (const-div -> magic mul)
      int pos = i - h*NEDGES;
      float v = el[srcs[pos]*HEADS + h] + er[dsts[pos]*HEADS + h];
      v = v >= 0.f ? v : 0.2f*v;
      wb[i] = __expf(v);
    }
  }
}

// ---------------- MFMA GEMM, bf16 output ----------------
// SPLIT=1 (layer 0): (Ah+Al)*Bh split-2. SPLIT=0 (layers 1,2): Ah*Bh only.
// XCD-aware swizzle: each XCD owns 20 exclusive bm strips.
template<bool SPLIT>
__global__ __launch_bounds__(256, 3) void k_gemm_mfma(
    const unsigned short* __restrict__ Ah, const unsigned short* __restrict__ Al,
    const unsigned short* __restrict__ Bh,
    unsigned short* __restrict__ Fh, int K) {
  __shared__ short sAh[128*32];
  __shared__ short sAl[SPLIT ? 128*32 : 16];
  __shared__ short sBh[128*32];
  const int t = threadIdx.x;
  const int w = t >> 6, l = t & 63;
  const int b = blockIdx.x;
  const int xcd = b & 7, kk = b >> 3;
  const int bm = xcd*20 + (kk >> 3), bn = kk & 7;
  const int m0 = (w >> 1) * 64, n0 = (w & 1) * 64;

  f32x4 acc[4][4];
  #pragma unroll
  for (int i = 0; i < 4; ++i)
    #pragma unroll
    for (int j = 0; j < 4; ++j) acc[i][j] = (f32x4){0.f, 0.f, 0.f, 0.f};

  const int srow = t >> 2, koct = (t & 3) * 8;
  const size_t r64 = (size_t)64 * K;
  const unsigned short* gAh = Ah + (size_t)(bm*128 + srow)*K + koct;
  const unsigned short* gAl = Al + (size_t)(bm*128 + srow)*K + koct;
  const unsigned short* gBh = Bh + (size_t)(bn*128 + srow)*K + koct;
  char* lAh = (char*)sAh + w*1024;
  char* lAl = (char*)sAl + w*1024;
  char* lBh = (char*)sBh + w*1024;

  const int fr = l & 15, fq = l >> 4;

  for (int k0 = 0; k0 < K; k0 += 32) {
    async_ld16(lAh,        gAh + k0);
    async_ld16(lAh + 4096, gAh + k0 + r64);
    if (SPLIT) {
      async_ld16(lAl,        gAl + k0);
      async_ld16(lAl + 4096, gAl + k0 + r64);
    }
    async_ld16(lBh,        gBh + k0);
    async_ld16(lBh + 4096, gBh + k0 + r64);
    __syncthreads();

    short8 bhv[4];
    #pragma unroll
    for (int nt = 0; nt < 4; ++nt)
      bhv[nt] = *(const short8*)&sBh[(n0 + nt*16 + fr)*32 + fq*8];
    #pragma unroll
    for (int mt = 0; mt < 4; ++mt) {
      int off = (m0 + mt*16 + fr)*32 + fq*8;
      short8 ah = *(const short8*)&sAh[off];
      #pragma unroll
      for (int nt = 0; nt < 4; ++nt)
        acc[mt][nt] = __builtin_amdgcn_mfma_f32_16x16x32_bf16(ah, bhv[nt], acc[mt][nt], 0, 0, 0);
      if (SPLIT) {
        short8 al = *(const short8*)&sAl[off];
        #pragma unroll
        for (int nt = 0; nt < 4; ++nt)
          acc[mt][nt] = __builtin_amdgcn_mfma_f32_16x16x32_bf16(al, bhv[nt], acc[mt][nt], 0, 0, 0);
      }
    }
    __syncthreads();
  }

  #pragma unroll
  for (int mt = 0; mt < 4; ++mt)
    #pragma unroll
    for (int nt = 0; nt < 4; ++nt) {
      size_t base = (size_t)(bm*128 + m0 + mt*16 + fq*4)*MCOLS + bn*128 + n0 + nt*16 + fr;
      Fh[base          ] = f2bf(acc[mt][nt][0]);
      Fh[base + MCOLS  ] = f2bf(acc[mt][nt][1]);
      Fh[base + 2*MCOLS] = f2bf(acc[mt][nt][2]);
      Fh[base + 3*MCOLS] = f2bf(acc[mt][nt][3]);
    }
}

// ======== XCD-sliced aggregation engine ========
// Slice s = blockIdx&7 -> XCD s (round-robin dispatch). Slice covers 256 B of
// each fsh row (head s>>1, half s&1) -> per-XCD gather working set 5.1 MB;
// a 2-phase src-range sweep (src<10000 / >=10000) halves it to ~2.6 MB,
// L2-resident. Wave geometry: 4 edge-groups x 16 lanes; each lane owns 8 dims
// (16 B) of the slice; 1 wave instruction gathers 4 edges' 256-B slices.
__device__ __forceinline__ void slice_gather(
    const char* __restrict__ fb, const float* __restrict__ wbh,
    const int* __restrict__ srcs, int beg, int end, unsigned soff, int g,
    float* ac, float& den) {
  #pragma unroll
  for (int ph = 0; ph < 2; ++ph) {
    const int lo = ph * (NNODES/2);
    const int hi = lo + (NNODES/2);
    int e = beg + g;
    int sr0 = 0; float wg0 = 0.f;
    if (e < end) {
      int sr = srcs[e];
      float wv = wbh[e];
      bool inr = (sr >= lo) & (sr < hi);
      sr0 = inr ? sr : 0;
      wg0 = inr ? wv : 0.f;
    }
    for (int i = beg; i < end; i += 4) {
      const uint4 u = *(const uint4*)(fb + ((unsigned)sr0*2048u + soff));
      int e2 = i + 4 + g;
      int sr1 = 0; float wg1 = 0.f;
      if (e2 < end) {
        int sr = srcs[e2];
        float wv = wbh[e2];
        bool inr = (sr >= lo) & (sr < hi);
        sr1 = inr ? sr : 0;
        wg1 = inr ? wv : 0.f;
      }
      den += wg0;
      ac[0] = fmaf(wg0, blo(u.x), ac[0]);
      ac[1] = fmaf(wg0, bhi(u.x), ac[1]);
      ac[2] = fmaf(wg0, blo(u.y), ac[2]);
      ac[3] = fmaf(wg0, bhi(u.y), ac[3]);
      ac[4] = fmaf(wg0, blo(u.z), ac[4]);
      ac[5] = fmaf(wg0, bhi(u.z), ac[5]);
      ac[6] = fmaf(wg0, blo(u.w), ac[6]);
      ac[7] = fmaf(wg0, bhi(u.w), ac[7]);
      sr0 = sr1; wg0 = wg1;
    }
  }
}

// ---------------- fused aggregation (layers 0,1), sliced ----------------
// el_next/er_next are atomically accumulated (pre-zeroed via hipMemsetAsync).
__global__ __launch_bounds__(256) void k_agg_f(
    const unsigned short* __restrict__ fsh, const float* __restrict__ wbuf,
    const int* __restrict__ row_ptr, const int* __restrict__ srcs,
    const float* __restrict__ bias,
    const float* __restrict__ WalN, const float* __restrict__ WredN,
    unsigned short* __restrict__ Ahi,
    float* __restrict__ el_next, float* __restrict__ er_next) {
  const int b = blockIdx.x;
  const int s = b & 7;
  const int gb = b >> 3;
  const int t = threadIdx.x;
  const int wv = t >> 6, lane = t & 63;
  const int g = lane >> 4, sl = lane & 15;
  const int head = s >> 1, half = s & 1;
  const int k0 = head*DDIM + half*128 + sl*8;
  const unsigned soff = (unsigned)(s*256 + sl*16);
  const char* fb = (const char*)fsh;
  const float* wbh = wbuf + (size_t)head*NEDGES;

  const int nbase = gb*20 + wv*5;
  for (int nn = 0; nn < 5; ++nn) {
    const int n = nbase + nn;
    if (n >= NNODES) {
      if (lane < 16) {
        uint4 z = {0,0,0,0};
        *(uint4*)&Ahi[(size_t)n*MCOLS + k0] = z;
      }
      continue;
    }
    const int beg = row_ptr[n], end = row_ptr[n+1];
    float den = 0.f;
    float ac[8] = {0.f,0.f,0.f,0.f,0.f,0.f,0.f,0.f};
    slice_gather(fb, wbh, srcs, beg, end, soff, g, ac, den);
    // reduce across the 4 edge-groups
    #pragma unroll
    for (int j = 0; j < 8; ++j) {
      ac[j] += __shfl_xor(ac[j], 16);
      ac[j] += __shfl_xor(ac[j], 32);
    }
    den += __shfl_xor(den, 16);
    den += __shfl_xor(den, 32);
    const float inv = den > 0.f ? 1.f/den : 0.f;
    const float4 bv0 = *(const float4*)&bias[k0];
    const float4 bv1 = *(const float4*)&bias[k0 + 4];
    float o[8];
    o[0] = fmaxf(ac[0]*inv + bv0.x, 0.f);
    o[1] = fmaxf(ac[1]*inv + bv0.y, 0.f);
    o[2] = fmaxf(ac[2]*inv + bv0.z, 0.f);
    o[3] = fmaxf(ac[3]*inv + bv0.w, 0.f);
    o[4] = fmaxf(ac[4]*inv + bv1.x, 0.f);
    o[5] = fmaxf(ac[5]*inv + bv1.y, 0.f);
    o[6] = fmaxf(ac[6]*inv + bv1.z, 0.f);
    o[7] = fmaxf(ac[7]*inv + bv1.w, 0.f);
    if (lane < 16) {
      uint4 hp;
      hp.x = (unsigned)f2bf(o[0]) | ((unsigned)f2bf(o[1]) << 16);
      hp.y = (unsigned)f2bf(o[2]) | ((unsigned)f2bf(o[3]) << 16);
      hp.z = (unsigned)f2bf(o[4]) | ((unsigned)f2bf(o[5]) << 16);
      hp.w = (unsigned)f2bf(o[6]) | ((unsigned)f2bf(o[7]) << 16);
      *(uint4*)&Ahi[(size_t)n*MCOLS + k0] = hp;
    }
    // el/er partials over this lane's 8 feature dims (all 4 next-layer heads)
    float p[8] = {0.f,0.f,0.f,0.f,0.f,0.f,0.f,0.f};
    #pragma unroll
    for (int j = 0; j < 8; ++j) {
      const float4 wa = *(const float4*)&WalN[(k0+j)*HEADS];
      const float4 wr = *(const float4*)&WredN[(k0+j)*HEADS];
      p[0] = fmaf(o[j], wa.x, p[0]);
      p[1] = fmaf(o[j], wa.y, p[1]);
      p[2] = fmaf(o[j], wa.z, p[2]);
      p[3] = fmaf(o[j], wa.w, p[3]);
      p[4] = fmaf(o[j], wr.x, p[4]);
      p[5] = fmaf(o[j], wr.y, p[5]);
      p[6] = fmaf(o[j], wr.z, p[6]);
      p[7] = fmaf(o[j], wr.w, p[7]);
    }
    // reduce over the 16 lanes of the group (dims of the slice)
    #pragma unroll
    for (int off2 = 1; off2 < 16; off2 <<= 1)
      #pragma unroll
      for (int j = 0; j < 8; ++j) p[j] += __shfl_xor(p[j], off2);
    if (lane == 0) {
      #pragma unroll
      for (int j = 0; j < 4; ++j) atomicAdd(&el_next[n*HEADS + j], p[j]);
      #pragma unroll
      for (int j = 0; j < 4; ++j) atomicAdd(&er_next[n*HEADS + j], p[4+j]);
    }
  }
}

// ---------------- final aggregation (layer 2), sliced -> per-head partials ----
// opart layout [head][NNODES][DDIM] fp32 (aliases dead Ahi+Alo region).
__global__ __launch_bounds__(256) void k_agg_out(
    const unsigned short* __restrict__ fsh, const float* __restrict__ wbuf,
    const int* __restrict__ row_ptr, const int* __restrict__ srcs,
    const float* __restrict__ bias, float* __restrict__ opart) {
  const int b = blockIdx.x;
  const int s = b & 7;
  const int gb = b >> 3;
  const int t = threadIdx.x;
  const int wv = t >> 6, lane = t & 63;
  const int g = lane >> 4, sl = lane & 15;
  const int head = s >> 1, half = s & 1;
  const int k0 = head*DDIM + half*128 + sl*8;
  const unsigned soff = (unsigned)(s*256 + sl*16);
  const char* fb = (const char*)fsh;
  const float* wbh = wbuf + (size_t)head*NEDGES;

  const int nbase = gb*20 + wv*5;      // grid covers exactly NNODES
  for (int nn = 0; nn < 5; ++nn) {
    const int n = nbase + nn;
    const int beg = row_ptr[n], end = row_ptr[n+1];
    float den = 0.f;
    float ac[8] = {0.f,0.f,0.f,0.f,0.f,0.f,0.f,0.f};
    slice_gather(fb, wbh, srcs, beg, end, soff, g, ac, den);
    #pragma unroll
    for (int j = 0; j < 8; ++j) {
      ac[j] += __shfl_xor(ac[j], 16);
      ac[j] += __shfl_xor(ac[j], 32);
    }
    den += __shfl_xor(den, 16);
    den += __shfl_xor(den, 32);
    const float inv = den > 0.f ? 1.f/den : 0.f;
    const float4 bv0 = *(const float4*)&bias[k0];
    const float4 bv1 = *(const float4*)&bias[k0 + 4];
    if (lane < 16) {
      float4 v0, v1;
      v0.x = ac[0]*inv + bv0.x;
      v0.y = ac[1]*inv + bv0.y;
      v0.z = ac[2]*inv + bv0.z;
      v0.w = ac[3]*inv + bv0.w;
      v1.x = ac[4]*inv + bv1.x;
      v1.y = ac[5]*inv + bv1.y;
      v1.z = ac[6]*inv + bv1.z;
      v1.w = ac[7]*inv + bv1.w;
      size_t ob = (size_t)head*NNODES*DDIM + (size_t)n*DDIM + half*128 + sl*8;
      *(float4*)&opart[ob]     = v0;
      *(float4*)&opart[ob + 4] = v1;
    }
  }
}

// ---------------- combine per-head partials -> head mean ----------------
__global__ __launch_bounds__(256) void k_combine(
    const float* __restrict__ opart, float* __restrict__ out) {
  const size_t i = (size_t)blockIdx.x*256 + threadIdx.x;
  const size_t NH = (size_t)NNODES*DDIM;
  out[i] = 0.25f*((opart[i] + opart[i + NH]) + (opart[i + 2*NH] + opart[i + 3*NH]));
}

extern "C" void kernel_launch(void* const* d_in, const int* in_sizes, int n_in,
                              void* d_out, int out_size, void* d_ws, size_t ws_size,
                              hipStream_t stream) {
  const float* x   = (const float*)d_in[0];
  const int*   src = (const int*)d_in[1];
  const int*   dst = (const int*)d_in[2];
  const float* Wsrc[3] = {(const float*)d_in[3], (const float*)d_in[8],  (const float*)d_in[13]};
  const float* Wdst[3] = {(const float*)d_in[4], (const float*)d_in[9],  (const float*)d_in[14]};
  const float* al[3]   = {(const float*)d_in[5], (const float*)d_in[10], (const float*)d_in[15]};
  const float* ar[3]   = {(const float*)d_in[6], (const float*)d_in[11], (const float*)d_in[16]};
  const float* bb[3]   = {(const float*)d_in[7], (const float*)d_in[12], (const float*)d_in[17]};

  char* ws = (char*)d_ws;
  size_t off = 0;
  auto alloc = [&](size_t bytes) { void* p = ws + off; off += (bytes + 255) & ~255ull; return p; };
  unsigned short* fshB = (unsigned short*)alloc((size_t)NPAD*MCOLS*2);  // bf16 fs
  unsigned short* Ahi = (unsigned short*)alloc((size_t)NPAD*MCOLS*2);
  unsigned short* Alo = (unsigned short*)alloc((size_t)NPAD*MCOLS*2);
  unsigned short* Wth = (unsigned short*)alloc((size_t)MCOLS*MCOLS*2);
  float* elA  = (float*)alloc((size_t)NNODES*HEADS*4);
  float* elB  = (float*)alloc((size_t)NNODES*HEADS*4);
  float* erA  = (float*)alloc((size_t)NNODES*HEADS*4);
  float* erB  = (float*)alloc((size_t)NNODES*HEADS*4);
  float* wbuf = (float*)alloc((size_t)NEDGES*HEADS*4);
  float* WredB[3]; float* WalB[3];
  for (int l = 0; l < 3; ++l) {
    WredB[l] = (float*)alloc(1024*HEADS*4);
    WalB[l]  = (float*)alloc(1024*HEADS*4);
  }
  int* deg     = (int*)alloc((size_t)NNODES*4);
  int* row_ptr = (int*)alloc((size_t)(NNODES+1)*4);
  int* cursor  = (int*)alloc((size_t)NNODES*4);
  int* srcs    = (int*)alloc((size_t)NEDGES*4);
  int* dsts    = (int*)alloc((size_t)NEDGES*4);
  (void)ws_size; (void)in_sizes; (void)n_in; (void)out_size;
  // layer-2 per-head partials alias the (then-dead) contiguous Ahi+Alo region:
  // need 4*20000*256*4 B = 81.92 MB <= 2 * 41.94 MB. Ahi/Alo are dead after
  // the layer-2 GEMM consumed Ahi.
  float* opart = (float*)Ahi;

  // CSR build (graph identical across layers)
  k_zero<<<(NNODES+255)/256, 256, 0, stream>>>(deg, NNODES);
  k_hist<<<(NEDGES+255)/256, 256, 0, stream>>>(dst, deg, NEDGES);
  k_scan<<<1, 1024, 0, stream>>>(deg, row_ptr, cursor);
  k_fill<<<(NEDGES+255)/256, 256, 0, stream>>>(src, dst, cursor, srcs, dsts, NEDGES);

  // all folds in one launch
  k_fold_all<<<5120, 256, 0, stream>>>(
      Wdst[0], ar[0], WredB[0], Wsrc[0], al[0], WalB[0],
      Wdst[1], ar[1], WredB[1], Wsrc[1], al[1], WalB[1],
      Wdst[2], ar[2], WredB[2], Wsrc[2], al[2], WalB[2]);

  // layer-0 prep: split-bf16 A + el0/er0 in one pass
  k_prep0<<<NPAD, 256, 0, stream>>>(x, WalB[0], WredB[0], Ahi, Alo, elA, erA);

  float* el_cur = elA; float* el_nxt = elB;
  float* er_cur = erA; float* er_nxt = erB;
  const int Fin[3] = {512, 1024, 1024};
  const int E4 = NEDGES*HEADS;
  for (int l = 0; l < 3; ++l) {
    int K = Fin[l];
    k_cvtw_wgt<<<K + (E4 + 255)/256, 256, 0, stream>>>(
        Wsrc[l], Wth, K, el_cur, er_cur, srcs, dsts, wbuf, E4);
    if (l == 0)
      k_gemm_mfma<true><<<NBM*8, 256, 0, stream>>>(Ahi, Alo, Wth, fshB, K);
    else
      k_gemm_mfma<false><<<NBM*8, 256, 0, stream>>>(Ahi, Alo, Wth, fshB, K);
    if (l < 2) {
      hipMemsetAsync(el_nxt, 0, (size_t)NNODES*HEADS*4, stream);
      hipMemsetAsync(er_nxt, 0, (size_t)NNODES*HEADS*4, stream);
      // 1024 node-groups (20 nodes each, 4 waves x 5) x 8 slices
      k_agg_f<<<1024*8, 256, 0, stream>>>(fshB, wbuf, row_ptr, srcs, bb[l],
                                          WalB[l+1], WredB[l+1], Ahi, el_nxt, er_nxt);
      float* t1 = el_cur; el_cur = el_nxt; el_nxt = t1;
      float* t2 = er_cur; er_cur = er_nxt; er_nxt = t2;
    } else {
      // 1000 node-groups (exactly NNODES) x 8 slices, then head-mean combine
      k_agg_out<<<1000*8, 256, 0, stream>>>(fshB, wbuf, row_ptr, srcs, bb[l],
                                            opart);
      k_combine<<<(NNODES*DDIM)/256, 256, 0, stream>>>(opart, (float*)d_out);
    }
  }
}

// Round 8
// 1180.177 us; speedup vs baseline: 1.1532x; 1.1532x over previous
//
#include <hip/hip_runtime.h>
#include <hip/hip_bf16.h>
#include <math.h>

#define NNODES 20000
#define NPAD   20480   // 160 * 128 (160 bm strips -> 20 per XCD)
#define NBM    160
#define NEDGES 320000
#define HEADS  4
#define DDIM   256
#define MCOLS  1024   // H*D

typedef __attribute__((ext_vector_type(8))) short short8;
typedef __attribute__((ext_vector_type(4))) float f32x4;

// bf16 helpers (bit-level, RNE)
__device__ __forceinline__ unsigned short f2bf(float f) {
  unsigned u = __float_as_uint(f);
  unsigned r = (u + 0x7fffu + ((u >> 16) & 1u)) >> 16;
  return (unsigned short)r;
}
__device__ __forceinline__ float bf2f(unsigned short h) {
  return __uint_as_float(((unsigned)h) << 16);
}
// unpack packed bf16 pair from a uint
__device__ __forceinline__ float blo(unsigned v) { return __uint_as_float(v << 16); }
__device__ __forceinline__ float bhi(unsigned v) { return __uint_as_float(v & 0xffff0000u); }

__device__ __forceinline__ void async_ld16(void* lds, const void* g) {
  __builtin_amdgcn_global_load_lds(
      (const __attribute__((address_space(1))) unsigned int*)g,
      (__attribute__((address_space(3))) unsigned int*)lds, 16, 0, 0);
}

// ---------------- CSR build (by dst) ----------------
__global__ void k_zero(int* deg, int n) {
  int i = blockIdx.x*blockDim.x + threadIdx.x;
  if (i < n) deg[i] = 0;
}
__global__ void k_hist(const int* __restrict__ dst, int* deg, int e) {
  int i = blockIdx.x*blockDim.x + threadIdx.x;
  if (i < e) atomicAdd(&deg[dst[i]], 1);
}
__global__ void k_scan(const int* __restrict__ deg, int* row_ptr, int* cursor) {
  __shared__ int sm[1024];
  int t = threadIdx.x;
  const int CH = 20;
  int base = t*CH;
  int s = 0;
  #pragma unroll
  for (int i = 0; i < CH; ++i) { int idx = base+i; if (idx < NNODES) s += deg[idx]; }
  int val = s;
  sm[t] = s; __syncthreads();
  for (int off = 1; off < 1024; off <<= 1) {
    int add = (t >= off) ? sm[t-off] : 0;
    __syncthreads();
    val += add; sm[t] = val;
    __syncthreads();
  }
  int run = val - s;
  for (int i = 0; i < CH; ++i) {
    int idx = base+i;
    if (idx < NNODES) { row_ptr[idx] = run; cursor[idx] = run; run += deg[idx]; }
  }
  if (t == 0) row_ptr[NNODES] = NEDGES;
}
__global__ void k_fill(const int* __restrict__ src, const int* __restrict__ dst,
                       int* cursor, int* srcs_sorted, int* dsts_sorted, int e) {
  int i = blockIdx.x*blockDim.x + threadIdx.x;
  if (i < e) {
    int d = dst[i];
    int pos = atomicAdd(&cursor[d], 1);
    srcs_sorted[pos] = src[i];
    dsts_sorted[pos] = d;
  }
}

// ---------------- all six folds in one launch ----------------
__device__ __forceinline__ void fold_body(const float* __restrict__ W,
                                          const float* __restrict__ v,
                                          float* __restrict__ F, int K, int bb) {
  int wave = threadIdx.x >> 6, lane = threadIdx.x & 63;
  int p = bb*4 + wave;            // p < K*4
  int k = p >> 2, h = p & 3;
  const float4 wv = *(const float4*)&W[(size_t)k*MCOLS + h*DDIM + lane*4];
  const float4 av = *(const float4*)&v[h*DDIM + lane*4];
  float s = wv.x*av.x + wv.y*av.y + wv.z*av.z + wv.w*av.w;
  for (int off = 32; off; off >>= 1) s += __shfl_xor(s, off);
  if (lane == 0) F[k*HEADS + h] = s;
}
__global__ __launch_bounds__(256) void k_fold_all(
    const float* Wd0, const float* ar0, float* F0,
    const float* Ws0, const float* al0, float* G0,
    const float* Wd1, const float* ar1, float* F1,
    const float* Ws1, const float* al1, float* G1,
    const float* Wd2, const float* ar2, float* F2,
    const float* Ws2, const float* al2, float* G2) {
  int b = blockIdx.x;
  if      (b < 512)  fold_body(Wd0, ar0, F0, 512,  b);
  else if (b < 1024) fold_body(Ws0, al0, G0, 512,  b - 512);
  else if (b < 2048) fold_body(Wd1, ar1, F1, 1024, b - 1024);
  else if (b < 3072) fold_body(Ws1, al1, G1, 1024, b - 2048);
  else if (b < 4096) fold_body(Wd2, ar2, F2, 1024, b - 3072);
  else               fold_body(Ws2, al2, G2, 1024, b - 4096);
}

// ---------------- layer-0 prep: split-bf16 A + el0/er0, one pass over x ----------
__global__ __launch_bounds__(256) void k_prep0(
    const float* __restrict__ x, const float* __restrict__ Wal,
    const float* __restrict__ Wred,
    unsigned short* __restrict__ hi, unsigned short* __restrict__ lo,
    float* __restrict__ el, float* __restrict__ er) {
  __shared__ float red_sm[4][8];
  int n = blockIdx.x, t = threadIdx.x;
  if (n >= NNODES) {
    *(ushort2*)&hi[(size_t)n*512 + 2*t] = (ushort2){0,0};
    *(ushort2*)&lo[(size_t)n*512 + 2*t] = (ushort2){0,0};
    return;
  }
  float2 xv = *(const float2*)&x[(size_t)n*512 + 2*t];
  ushort2 h2, l2;
  h2.x = f2bf(xv.x); l2.x = f2bf(xv.x - bf2f(h2.x));
  h2.y = f2bf(xv.y); l2.y = f2bf(xv.y - bf2f(h2.y));
  *(ushort2*)&hi[(size_t)n*512 + 2*t] = h2;
  *(ushort2*)&lo[(size_t)n*512 + 2*t] = l2;
  const float4 wa0 = *(const float4*)&Wal[(2*t)*4];
  const float4 wa1 = *(const float4*)&Wal[(2*t+1)*4];
  const float4 wr0 = *(const float4*)&Wred[(2*t)*4];
  const float4 wr1 = *(const float4*)&Wred[(2*t+1)*4];
  float p[8];
  p[0] = xv.x*wa0.x + xv.y*wa1.x;
  p[1] = xv.x*wa0.y + xv.y*wa1.y;
  p[2] = xv.x*wa0.z + xv.y*wa1.z;
  p[3] = xv.x*wa0.w + xv.y*wa1.w;
  p[4] = xv.x*wr0.x + xv.y*wr1.x;
  p[5] = xv.x*wr0.y + xv.y*wr1.y;
  p[6] = xv.x*wr0.z + xv.y*wr1.z;
  p[7] = xv.x*wr0.w + xv.y*wr1.w;
  for (int off = 32; off; off >>= 1)
    #pragma unroll
    for (int j = 0; j < 8; ++j) p[j] += __shfl_xor(p[j], off);
  if ((t & 63) == 0)
    #pragma unroll
    for (int j = 0; j < 8; ++j) red_sm[t >> 6][j] = p[j];
  __syncthreads();
  if (t < 8) {
    float v = (red_sm[0][t] + red_sm[1][t]) + (red_sm[2][t] + red_sm[3][t]);
    if (t < 4) el[n*HEADS + t] = v;
    else       er[n*HEADS + (t-4)] = v;
  }
}

// ---------------- combined: W transpose->bf16 + per-edge softmax weights ----------
// wb layout is HEAD-MAJOR: wb[h*NEDGES + pos].
__global__ __launch_bounds__(256) void k_cvtw_wgt(
    const float* __restrict__ W, unsigned short* __restrict__ Th, int K,
    const float* __restrict__ el, const float* __restrict__ er,
    const int* __restrict__ srcs, const int* __restrict__ dsts,
    float* __restrict__ wb, int e4) {
  int b = blockIdx.x;
  if (b < K) {   // transpose part: K blocks (32 n-tiles x K/32 k-tiles)
    __shared__ float sm[32][33];
    int n0 = (b & 31)*32, k0 = (b >> 5)*32;
    int t = threadIdx.x;
    int r = t >> 3, c4 = (t & 7)*4;
    *(float4*)&sm[r][c4] = *(const float4*)&W[(size_t)(k0 + r)*MCOLS + n0 + c4];
    __syncthreads();
    ushort4 h;
    h.x = f2bf(sm[c4+0][r]);
    h.y = f2bf(sm[c4+1][r]);
    h.z = f2bf(sm[c4+2][r]);
    h.w = f2bf(sm[c4+3][r]);
    *(ushort4*)&Th[(size_t)(n0 + r)*K + k0 + c4] = h;
  } else {
    int i = (b - K)*256 + threadIdx.x;
    if (i < e4) {
      int h = i / NEDGES;          // head plane (const-div -> magic mul)
      int pos = i - h*NEDGES;
      float v = el[srcs[pos]*HEADS + h] + er[dsts[pos]*HEADS + h];
      v = v >= 0.f ? v : 0.2f*v;
      wb[i] = __expf(v);
    }
  }
}

// ---------------- MFMA GEMM, bf16 output ----------------
// SPLIT=1 (layer 0): (Ah+Al)*Bh split-2. SPLIT=0 (layers 1,2): Ah*Bh only.
// XCD-aware swizzle: each XCD owns 20 exclusive bm strips.
template<bool SPLIT>
__global__ __launch_bounds__(256, 3) void k_gemm_mfma(
    const unsigned short* __restrict__ Ah, const unsigned short* __restrict__ Al,
    const unsigned short* __restrict__ Bh,
    unsigned short* __restrict__ Fh, int K) {
  __shared__ short sAh[128*32];
  __shared__ short sAl[SPLIT ? 128*32 : 16];
  __shared__ short sBh[128*32];
  const int t = threadIdx.x;
  const int w = t >> 6, l = t & 63;
  const int b = blockIdx.x;
  const int xcd = b & 7, kk = b >> 3;
  const int bm = xcd*20 + (kk >> 3), bn = kk & 7;
  const int m0 = (w >> 1) * 64, n0 = (w & 1) * 64;

  f32x4 acc[4][4];
  #pragma unroll
  for (int i = 0; i < 4; ++i)
    #pragma unroll
    for (int j = 0; j < 4; ++j) acc[i][j] = (f32x4){0.f, 0.f, 0.f, 0.f};

  const int srow = t >> 2, koct = (t & 3) * 8;
  const size_t r64 = (size_t)64 * K;
  const unsigned short* gAh = Ah + (size_t)(bm*128 + srow)*K + koct;
  const unsigned short* gAl = Al + (size_t)(bm*128 + srow)*K + koct;
  const unsigned short* gBh = Bh + (size_t)(bn*128 + srow)*K + koct;
  char* lAh = (char*)sAh + w*1024;
  char* lAl = (char*)sAl + w*1024;
  char* lBh = (char*)sBh + w*1024;

  const int fr = l & 15, fq = l >> 4;

  for (int k0 = 0; k0 < K; k0 += 32) {
    async_ld16(lAh,        gAh + k0);
    async_ld16(lAh + 4096, gAh + k0 + r64);
    if (SPLIT) {
      async_ld16(lAl,        gAl + k0);
      async_ld16(lAl + 4096, gAl + k0 + r64);
    }
    async_ld16(lBh,        gBh + k0);
    async_ld16(lBh + 4096, gBh + k0 + r64);
    __syncthreads();

    short8 bhv[4];
    #pragma unroll
    for (int nt = 0; nt < 4; ++nt)
      bhv[nt] = *(const short8*)&sBh[(n0 + nt*16 + fr)*32 + fq*8];
    #pragma unroll
    for (int mt = 0; mt < 4; ++mt) {
      int off = (m0 + mt*16 + fr)*32 + fq*8;
      short8 ah = *(const short8*)&sAh[off];
      #pragma unroll
      for (int nt = 0; nt < 4; ++nt)
        acc[mt][nt] = __builtin_amdgcn_mfma_f32_16x16x32_bf16(ah, bhv[nt], acc[mt][nt], 0, 0, 0);
      if (SPLIT) {
        short8 al = *(const short8*)&sAl[off];
        #pragma unroll
        for (int nt = 0; nt < 4; ++nt)
          acc[mt][nt] = __builtin_amdgcn_mfma_f32_16x16x32_bf16(al, bhv[nt], acc[mt][nt], 0, 0, 0);
      }
    }
    __syncthreads();
  }

  #pragma unroll
  for (int mt = 0; mt < 4; ++mt)
    #pragma unroll
    for (int nt = 0; nt < 4; ++nt) {
      size_t base = (size_t)(bm*128 + m0 + mt*16 + fq*4)*MCOLS + bn*128 + n0 + nt*16 + fr;
      Fh[base          ] = f2bf(acc[mt][nt][0]);
      Fh[base + MCOLS  ] = f2bf(acc[mt][nt][1]);
      Fh[base + 2*MCOLS] = f2bf(acc[mt][nt][2]);
      Fh[base + 3*MCOLS] = f2bf(acc[mt][nt][3]);
    }
}

// ======== XCD-sliced aggregation, wave-per-node, 16-edges-in-flight ========
// Slice s = blockIdx&7 -> XCD s (round-robin; FETCH halving validated r6).
// Block = 256 thr = 4 INDEPENDENT waves; wave w owns node nbase+w, slice s.
// Wave lanes: el = lane>>4 (4 edge-groups) x sl = lane&15 (16 dim-lanes,
// 16B each -> 256B slice). Per 16-edge chunk each thread gathers u[4]
// -> 16 edges (rows) in flight per wave (the MLP r6 lacked); next chunk's
// srcs/wgt prefetched during FMA. Single pass (no phase sweep); per-XCD
// working set 5.25 MB ~ L2. No barriers, no LDS.
__device__ __forceinline__ void slice_node(
    const char* __restrict__ fb, const float* __restrict__ wbh,
    const int* __restrict__ srcs, int beg, int end, unsigned soff, int el,
    float* ac, float& den) {
  int   si[4];
  float wg[4];
  #pragma unroll
  for (int j = 0; j < 4; ++j) {
    int e = beg + 4*j + el;
    bool v = e < end;
    si[j] = v ? srcs[e] : 0;
    wg[j] = v ? wbh[e] : 0.f;
  }
  for (int chunk = beg; chunk < end; chunk += 16) {
    uint4 u[4];
    #pragma unroll
    for (int j = 0; j < 4; ++j)
      u[j] = *(const uint4*)(fb + ((unsigned)si[j]*2048u + soff));
    float wc[4];
    #pragma unroll
    for (int j = 0; j < 4; ++j) wc[j] = wg[j];
    int nchunk = chunk + 16;
    if (nchunk < end) {
      #pragma unroll
      for (int j = 0; j < 4; ++j) {
        int e = nchunk + 4*j + el;
        bool v = e < end;
        si[j] = v ? srcs[e] : 0;
        wg[j] = v ? wbh[e] : 0.f;
      }
    }
    #pragma unroll
    for (int j = 0; j < 4; ++j) {
      den += wc[j];
      ac[0] = fmaf(wc[j], blo(u[j].x), ac[0]);
      ac[1] = fmaf(wc[j], bhi(u[j].x), ac[1]);
      ac[2] = fmaf(wc[j], blo(u[j].y), ac[2]);
      ac[3] = fmaf(wc[j], bhi(u[j].y), ac[3]);
      ac[4] = fmaf(wc[j], blo(u[j].z), ac[4]);
      ac[5] = fmaf(wc[j], bhi(u[j].z), ac[5]);
      ac[6] = fmaf(wc[j], blo(u[j].w), ac[6]);
      ac[7] = fmaf(wc[j], bhi(u[j].w), ac[7]);
    }
  }
}

// ---------------- fused aggregation (layers 0,1), sliced ----------------
// el_next/er_next atomically accumulated (pre-zeroed via hipMemsetAsync).
__global__ __launch_bounds__(256) void k_agg_f(
    const unsigned short* __restrict__ fsh, const float* __restrict__ wbuf,
    const int* __restrict__ row_ptr, const int* __restrict__ srcs,
    const float* __restrict__ bias,
    const float* __restrict__ WalN, const float* __restrict__ WredN,
    unsigned short* __restrict__ Ahi,
    float* __restrict__ el_next, float* __restrict__ er_next) {
  const int b = blockIdx.x;
  const int s = b & 7;
  const int t = threadIdx.x;
  const int wv = t >> 6, lane = t & 63;
  const int el = lane >> 4, sl = lane & 15;
  const int head = s >> 1, half = s & 1;
  const int k0 = head*DDIM + half*128 + sl*8;
  const unsigned soff = (unsigned)(s*256 + sl*16);
  const char* fb = (const char*)fsh;
  const float* wbh = wbuf + (size_t)head*NEDGES;

  const int n = (b >> 3)*4 + wv;
  if (n >= NNODES) {
    if (lane < 16) {
      uint4 z = {0,0,0,0};
      *(uint4*)&Ahi[(size_t)n*MCOLS + k0] = z;
    }
    return;
  }
  const int beg = row_ptr[n], end = row_ptr[n+1];
  float den = 0.f;
  float ac[8] = {0.f,0.f,0.f,0.f,0.f,0.f,0.f,0.f};
  slice_node(fb, wbh, srcs, beg, end, soff, el, ac, den);
  // reduce across the 4 edge-groups
  #pragma unroll
  for (int j = 0; j < 8; ++j) {
    ac[j] += __shfl_xor(ac[j], 16);
    ac[j] += __shfl_xor(ac[j], 32);
  }
  den += __shfl_xor(den, 16);
  den += __shfl_xor(den, 32);
  const float inv = den > 0.f ? 1.f/den : 0.f;
  const float4 bv0 = *(const float4*)&bias[k0];
  const float4 bv1 = *(const float4*)&bias[k0 + 4];
  float o[8];
  o[0] = fmaxf(ac[0]*inv + bv0.x, 0.f);
  o[1] = fmaxf(ac[1]*inv + bv0.y, 0.f);
  o[2] = fmaxf(ac[2]*inv + bv0.z, 0.f);
  o[3] = fmaxf(ac[3]*inv + bv0.w, 0.f);
  o[4] = fmaxf(ac[4]*inv + bv1.x, 0.f);
  o[5] = fmaxf(ac[5]*inv + bv1.y, 0.f);
  o[6] = fmaxf(ac[6]*inv + bv1.z, 0.f);
  o[7] = fmaxf(ac[7]*inv + bv1.w, 0.f);
  if (lane < 16) {
    uint4 hp;
    hp.x = (unsigned)f2bf(o[0]) | ((unsigned)f2bf(o[1]) << 16);
    hp.y = (unsigned)f2bf(o[2]) | ((unsigned)f2bf(o[3]) << 16);
    hp.z = (unsigned)f2bf(o[4]) | ((unsigned)f2bf(o[5]) << 16);
    hp.w = (unsigned)f2bf(o[6]) | ((unsigned)f2bf(o[7]) << 16);
    *(uint4*)&Ahi[(size_t)n*MCOLS + k0] = hp;
  }
  // el/er partials over this lane's 8 feature dims (all 4 next-layer heads)
  float p[8] = {0.f,0.f,0.f,0.f,0.f,0.f,0.f,0.f};
  #pragma unroll
  for (int j = 0; j < 8; ++j) {
    const float4 wa = *(const float4*)&WalN[(k0+j)*HEADS];
    const float4 wr = *(const float4*)&WredN[(k0+j)*HEADS];
    p[0] = fmaf(o[j], wa.x, p[0]);
    p[1] = fmaf(o[j], wa.y, p[1]);
    p[2] = fmaf(o[j], wa.z, p[2]);
    p[3] = fmaf(o[j], wa.w, p[3]);
    p[4] = fmaf(o[j], wr.x, p[4]);
    p[5] = fmaf(o[j], wr.y, p[5]);
    p[6] = fmaf(o[j], wr.z, p[6]);
    p[7] = fmaf(o[j], wr.w, p[7]);
  }
  // reduce over the 16 dim-lanes
  #pragma unroll
  for (int off2 = 1; off2 < 16; off2 <<= 1)
    #pragma unroll
    for (int j = 0; j < 8; ++j) p[j] += __shfl_xor(p[j], off2);
  if (lane == 0) {
    #pragma unroll
    for (int j = 0; j < 4; ++j) atomicAdd(&el_next[n*HEADS + j], p[j]);
    #pragma unroll
    for (int j = 0; j < 4; ++j) atomicAdd(&er_next[n*HEADS + j], p[4+j]);
  }
}

// ---------------- final aggregation (layer 2), sliced -> per-head partials ----
// opart layout [head][NNODES][DDIM] fp32 (aliases dead Ahi+Alo region).
__global__ __launch_bounds__(256) void k_agg_out(
    const unsigned short* __restrict__ fsh, const float* __restrict__ wbuf,
    const int* __restrict__ row_ptr, const int* __restrict__ srcs,
    const float* __restrict__ bias, float* __restrict__ opart) {
  const int b = blockIdx.x;
  const int s = b & 7;
  const int t = threadIdx.x;
  const int wv = t >> 6, lane = t & 63;
  const int el = lane >> 4, sl = lane & 15;
  const int head = s >> 1, half = s & 1;
  const int k0 = head*DDIM + half*128 + sl*8;
  const unsigned soff = (unsigned)(s*256 + sl*16);
  const char* fb = (const char*)fsh;
  const float* wbh = wbuf + (size_t)head*NEDGES;

  const int n = (b >> 3)*4 + wv;       // grid covers exactly NNODES
  const int beg = row_ptr[n], end = row_ptr[n+1];
  float den = 0.f;
  float ac[8] = {0.f,0.f,0.f,0.f,0.f,0.f,0.f,0.f};
  slice_node(fb, wbh, srcs, beg, end, soff, el, ac, den);
  #pragma unroll
  for (int j = 0; j < 8; ++j) {
    ac[j] += __shfl_xor(ac[j], 16);
    ac[j] += __shfl_xor(ac[j], 32);
  }
  den += __shfl_xor(den, 16);
  den += __shfl_xor(den, 32);
  const float inv = den > 0.f ? 1.f/den : 0.f;
  const float4 bv0 = *(const float4*)&bias[k0];
  const float4 bv1 = *(const float4*)&bias[k0 + 4];
  if (lane < 16) {
    float4 v0, v1;
    v0.x = ac[0]*inv + bv0.x;
    v0.y = ac[1]*inv + bv0.y;
    v0.z = ac[2]*inv + bv0.z;
    v0.w = ac[3]*inv + bv0.w;
    v1.x = ac[4]*inv + bv1.x;
    v1.y = ac[5]*inv + bv1.y;
    v1.z = ac[6]*inv + bv1.z;
    v1.w = ac[7]*inv + bv1.w;
    size_t ob = (size_t)head*NNODES*DDIM + (size_t)n*DDIM + half*128 + sl*8;
    *(float4*)&opart[ob]     = v0;
    *(float4*)&opart[ob + 4] = v1;
  }
}

// ---------------- combine per-head partials -> head mean ----------------
__global__ __launch_bounds__(256) void k_combine(
    const float* __restrict__ opart, float* __restrict__ out) {
  const size_t i = (size_t)blockIdx.x*256 + threadIdx.x;
  const size_t NH = (size_t)NNODES*DDIM;
  out[i] = 0.25f*((opart[i] + opart[i + NH]) + (opart[i + 2*NH] + opart[i + 3*NH]));
}

extern "C" void kernel_launch(void* const* d_in, const int* in_sizes, int n_in,
                              void* d_out, int out_size, void* d_ws, size_t ws_size,
                              hipStream_t stream) {
  const float* x   = (const float*)d_in[0];
  const int*   src = (const int*)d_in[1];
  const int*   dst = (const int*)d_in[2];
  const float* Wsrc[3] = {(const float*)d_in[3], (const float*)d_in[8],  (const float*)d_in[13]};
  const float* Wdst[3] = {(const float*)d_in[4], (const float*)d_in[9],  (const float*)d_in[14]};
  const float* al[3]   = {(const float*)d_in[5], (const float*)d_in[10], (const float*)d_in[15]};
  const float* ar[3]   = {(const float*)d_in[6], (const float*)d_in[11], (const float*)d_in[16]};
  const float* bb[3]   = {(const float*)d_in[7], (const float*)d_in[12], (const float*)d_in[17]};

  char* ws = (char*)d_ws;
  size_t off = 0;
  auto alloc = [&](size_t bytes) { void* p = ws + off; off += (bytes + 255) & ~255ull; return p; };
  unsigned short* fshB = (unsigned short*)alloc((size_t)NPAD*MCOLS*2);  // bf16 fs
  unsigned short* Ahi = (unsigned short*)alloc((size_t)NPAD*MCOLS*2);
  unsigned short* Alo = (unsigned short*)alloc((size_t)NPAD*MCOLS*2);
  unsigned short* Wth = (unsigned short*)alloc((size_t)MCOLS*MCOLS*2);
  float* elA  = (float*)alloc((size_t)NNODES*HEADS*4);
  float* elB  = (float*)alloc((size_t)NNODES*HEADS*4);
  float* erA  = (float*)alloc((size_t)NNODES*HEADS*4);
  float* erB  = (float*)alloc((size_t)NNODES*HEADS*4);
  float* wbuf = (float*)alloc((size_t)NEDGES*HEADS*4);
  float* WredB[3]; float* WalB[3];
  for (int l = 0; l < 3; ++l) {
    WredB[l] = (float*)alloc(1024*HEADS*4);
    WalB[l]  = (float*)alloc(1024*HEADS*4);
  }
  int* deg     = (int*)alloc((size_t)NNODES*4);
  int* row_ptr = (int*)alloc((size_t)(NNODES+1)*4);
  int* cursor  = (int*)alloc((size_t)NNODES*4);
  int* srcs    = (int*)alloc((size_t)NEDGES*4);
  int* dsts    = (int*)alloc((size_t)NEDGES*4);
  (void)ws_size; (void)in_sizes; (void)n_in; (void)out_size;
  // layer-2 per-head partials alias the (then-dead) contiguous Ahi+Alo region.
  float* opart = (float*)Ahi;

  // CSR build (graph identical across layers)
  k_zero<<<(NNODES+255)/256, 256, 0, stream>>>(deg, NNODES);
  k_hist<<<(NEDGES+255)/256, 256, 0, stream>>>(dst, deg, NEDGES);
  k_scan<<<1, 1024, 0, stream>>>(deg, row_ptr, cursor);
  k_fill<<<(NEDGES+255)/256, 256, 0, stream>>>(src, dst, cursor, srcs, dsts, NEDGES);

  // all folds in one launch
  k_fold_all<<<5120, 256, 0, stream>>>(
      Wdst[0], ar[0], WredB[0], Wsrc[0], al[0], WalB[0],
      Wdst[1], ar[1], WredB[1], Wsrc[1], al[1], WalB[1],
      Wdst[2], ar[2], WredB[2], Wsrc[2], al[2], WalB[2]);

  // layer-0 prep: split-bf16 A + el0/er0 in one pass
  k_prep0<<<NPAD, 256, 0, stream>>>(x, WalB[0], WredB[0], Ahi, Alo, elA, erA);

  float* el_cur = elA; float* el_nxt = elB;
  float* er_cur = erA; float* er_nxt = erB;
  const int Fin[3] = {512, 1024, 1024};
  const int E4 = NEDGES*HEADS;
  for (int l = 0; l < 3; ++l) {
    int K = Fin[l];
    k_cvtw_wgt<<<K + (E4 + 255)/256, 256, 0, stream>>>(
        Wsrc[l], Wth, K, el_cur, er_cur, srcs, dsts, wbuf, E4);
    if (l == 0)
      k_gemm_mfma<true><<<NBM*8, 256, 0, stream>>>(Ahi, Alo, Wth, fshB, K);
    else
      k_gemm_mfma<false><<<NBM*8, 256, 0, stream>>>(Ahi, Alo, Wth, fshB, K);
    if (l < 2) {
      hipMemsetAsync(el_nxt, 0, (size_t)NNODES*HEADS*4, stream);
      hipMemsetAsync(er_nxt, 0, (size_t)NNODES*HEADS*4, stream);
      // (NPAD/4) node-quads x 8 slices; wave-per-node
      k_agg_f<<<(NPAD/4)*8, 256, 0, stream>>>(fshB, wbuf, row_ptr, srcs, bb[l],
                                              WalB[l+1], WredB[l+1], Ahi, el_nxt, er_nxt);
      float* t1 = el_cur; el_cur = el_nxt; el_nxt = t1;
      float* t2 = er_cur; er_cur = er_nxt; er_nxt = t2;
    } else {
      // (NNODES/4) node-quads x 8 slices, then head-mean combine
      k_agg_out<<<(NNODES/4)*8, 256, 0, stream>>>(fshB, wbuf, row_ptr, srcs, bb[l],
                                                  opart);
      k_combine<<<(NNODES*DDIM)/256, 256, 0, stream>>>(opart, (float*)d_out);
    }
  }
}

// Round 10
// 705.553 us; speedup vs baseline: 1.9289x; 1.6727x over previous
//
#include <hip/hip_runtime.h>
#include <hip/hip_bf16.h>
#include <math.h>

#define NNODES 20000
#define NPAD   20480   // 160 * 128
#define NBM    160
#define NEDGES 320000
#define HEADS  4
#define DDIM   256
#define MCOLS  1024   // H*D

typedef __attribute__((ext_vector_type(8))) short short8;
typedef __attribute__((ext_vector_type(4))) float f32x4;

// bf16 helpers (bit-level, RNE)
__device__ __forceinline__ unsigned short f2bf(float f) {
  unsigned u = __float_as_uint(f);
  unsigned r = (u + 0x7fffu + ((u >> 16) & 1u)) >> 16;
  return (unsigned short)r;
}
__device__ __forceinline__ float bf2f(unsigned short h) {
  return __uint_as_float(((unsigned)h) << 16);
}
__device__ __forceinline__ float blo(unsigned v) { return __uint_as_float(v << 16); }
__device__ __forceinline__ float bhi(unsigned v) { return __uint_as_float(v & 0xffff0000u); }

__device__ __forceinline__ void async_ld16(void* lds, const void* g) {
  __builtin_amdgcn_global_load_lds(
      (const __attribute__((address_space(1))) unsigned int*)g,
      (__attribute__((address_space(3))) unsigned int*)lds, 16, 0, 0);
}

// ---------------- CSR build (by dst) ----------------
__global__ void k_zero(int* deg, int n) {
  int i = blockIdx.x*blockDim.x + threadIdx.x;
  if (i < n) deg[i] = 0;
}
__global__ void k_hist(const int* __restrict__ dst, int* deg, int e) {
  int i = blockIdx.x*blockDim.x + threadIdx.x;
  if (i < e) atomicAdd(&deg[dst[i]], 1);
}
__global__ void k_scan(const int* __restrict__ deg, int* row_ptr, int* cursor) {
  __shared__ int sm[1024];
  int t = threadIdx.x;
  const int CH = 20;
  int base = t*CH;
  int s = 0;
  #pragma unroll
  for (int i = 0; i < CH; ++i) { int idx = base+i; if (idx < NNODES) s += deg[idx]; }
  int val = s;
  sm[t] = s; __syncthreads();
  for (int off = 1; off < 1024; off <<= 1) {
    int add = (t >= off) ? sm[t-off] : 0;
    __syncthreads();
    val += add; sm[t] = val;
    __syncthreads();
  }
  int run = val - s;
  for (int i = 0; i < CH; ++i) {
    int idx = base+i;
    if (idx < NNODES) { row_ptr[idx] = run; cursor[idx] = run; run += deg[idx]; }
  }
  if (t == 0) row_ptr[NNODES] = NEDGES;
}
__global__ void k_fill(const int* __restrict__ src, const int* __restrict__ dst,
                       int* cursor, int* srcs_sorted, int* dsts_sorted, int e) {
  int i = blockIdx.x*blockDim.x + threadIdx.x;
  if (i < e) {
    int d = dst[i];
    int pos = atomicAdd(&cursor[d], 1);
    srcs_sorted[pos] = src[i];
    dsts_sorted[pos] = d;
  }
}

// ---------------- all six folds in one launch ----------------
__device__ __forceinline__ void fold_body(const float* __restrict__ W,
                                          const float* __restrict__ v,
                                          float* __restrict__ F, int K, int bb) {
  int wave = threadIdx.x >> 6, lane = threadIdx.x & 63;
  int p = bb*4 + wave;            // p < K*4
  int k = p >> 2, h = p & 3;
  const float4 wv = *(const float4*)&W[(size_t)k*MCOLS + h*DDIM + lane*4];
  const float4 av = *(const float4*)&v[h*DDIM + lane*4];
  float s = wv.x*av.x + wv.y*av.y + wv.z*av.z + wv.w*av.w;
  for (int off = 32; off; off >>= 1) s += __shfl_xor(s, off);
  if (lane == 0) F[k*HEADS + h] = s;
}
__global__ __launch_bounds__(256) void k_fold_all(
    const float* Wd0, const float* ar0, float* F0,
    const float* Ws0, const float* al0, float* G0,
    const float* Wd1, const float* ar1, float* F1,
    const float* Ws1, const float* al1, float* G1,
    const float* Wd2, const float* ar2, float* F2,
    const float* Ws2, const float* al2, float* G2) {
  int b = blockIdx.x;
  if      (b < 512)  fold_body(Wd0, ar0, F0, 512,  b);
  else if (b < 1024) fold_body(Ws0, al0, G0, 512,  b - 512);
  else if (b < 2048) fold_body(Wd1, ar1, F1, 1024, b - 1024);
  else if (b < 3072) fold_body(Ws1, al1, G1, 1024, b - 2048);
  else if (b < 4096) fold_body(Wd2, ar2, F2, 1024, b - 3072);
  else               fold_body(Ws2, al2, G2, 1024, b - 4096);
}

// ---------------- layer-0 prep: x -> bf16 table + el0/er0 ----------------
__global__ __launch_bounds__(256) void k_prep0(
    const float* __restrict__ x, const float* __restrict__ Wal,
    const float* __restrict__ Wred,
    unsigned short* __restrict__ xh,
    float* __restrict__ el, float* __restrict__ er) {
  __shared__ float red_sm[4][8];
  int n = blockIdx.x, t = threadIdx.x;
  if (n >= NNODES) {
    *(ushort2*)&xh[(size_t)n*512 + 2*t] = (ushort2){0,0};
    return;
  }
  float2 xv = *(const float2*)&x[(size_t)n*512 + 2*t];
  ushort2 h2;
  h2.x = f2bf(xv.x);
  h2.y = f2bf(xv.y);
  *(ushort2*)&xh[(size_t)n*512 + 2*t] = h2;
  const float4 wa0 = *(const float4*)&Wal[(2*t)*4];
  const float4 wa1 = *(const float4*)&Wal[(2*t+1)*4];
  const float4 wr0 = *(const float4*)&Wred[(2*t)*4];
  const float4 wr1 = *(const float4*)&Wred[(2*t+1)*4];
  float p[8];
  p[0] = xv.x*wa0.x + xv.y*wa1.x;
  p[1] = xv.x*wa0.y + xv.y*wa1.y;
  p[2] = xv.x*wa0.z + xv.y*wa1.z;
  p[3] = xv.x*wa0.w + xv.y*wa1.w;
  p[4] = xv.x*wr0.x + xv.y*wr1.x;
  p[5] = xv.x*wr0.y + xv.y*wr1.y;
  p[6] = xv.x*wr0.z + xv.y*wr1.z;
  p[7] = xv.x*wr0.w + xv.y*wr1.w;
  for (int off = 32; off; off >>= 1)
    #pragma unroll
    for (int j = 0; j < 8; ++j) p[j] += __shfl_xor(p[j], off);
  if ((t & 63) == 0)
    #pragma unroll
    for (int j = 0; j < 8; ++j) red_sm[t >> 6][j] = p[j];
  __syncthreads();
  if (t < 8) {
    float v = (red_sm[0][t] + red_sm[1][t]) + (red_sm[2][t] + red_sm[3][t]);
    if (t < 4) el[n*HEADS + t] = v;
    else       er[n*HEADS + (t-4)] = v;
  }
}

// ---------------- el/er for next layer from h (bf16, 1024-wide) ----------------
__global__ __launch_bounds__(256) void k_elr(
    const unsigned short* __restrict__ h, const float* __restrict__ Wal,
    const float* __restrict__ Wred,
    float* __restrict__ el, float* __restrict__ er) {
  __shared__ float red_sm[4][8];
  int n = blockIdx.x, t = threadIdx.x;
  ushort4 hv = *(const ushort4*)&h[(size_t)n*MCOLS + 4*t];
  float xv[4] = {bf2f(hv.x), bf2f(hv.y), bf2f(hv.z), bf2f(hv.w)};
  float p[8] = {0.f,0.f,0.f,0.f,0.f,0.f,0.f,0.f};
  #pragma unroll
  for (int j = 0; j < 4; ++j) {
    const float4 wa = *(const float4*)&Wal[(4*t + j)*HEADS];
    const float4 wr = *(const float4*)&Wred[(4*t + j)*HEADS];
    p[0] = fmaf(xv[j], wa.x, p[0]);
    p[1] = fmaf(xv[j], wa.y, p[1]);
    p[2] = fmaf(xv[j], wa.z, p[2]);
    p[3] = fmaf(xv[j], wa.w, p[3]);
    p[4] = fmaf(xv[j], wr.x, p[4]);
    p[5] = fmaf(xv[j], wr.y, p[5]);
    p[6] = fmaf(xv[j], wr.z, p[6]);
    p[7] = fmaf(xv[j], wr.w, p[7]);
  }
  for (int off = 32; off; off >>= 1)
    #pragma unroll
    for (int j = 0; j < 8; ++j) p[j] += __shfl_xor(p[j], off);
  if ((t & 63) == 0)
    #pragma unroll
    for (int j = 0; j < 8; ++j) red_sm[t >> 6][j] = p[j];
  __syncthreads();
  if (t < 8) {
    float v = (red_sm[0][t] + red_sm[1][t]) + (red_sm[2][t] + red_sm[3][t]);
    if (t < 4) el[n*HEADS + t] = v;
    else       er[n*HEADS + (t-4)] = v;
  }
}

// ---------------- combined: W transpose->bf16 + per-edge softmax weights ----------
// wb interleaved: wb[pos*4 + h].
__global__ __launch_bounds__(256) void k_cvtw_wgt(
    const float* __restrict__ W, unsigned short* __restrict__ Th, int K,
    const float* __restrict__ el, const float* __restrict__ er,
    const int* __restrict__ srcs, const int* __restrict__ dsts,
    float* __restrict__ wb, int e4) {
  int b = blockIdx.x;
  if (b < K) {   // transpose part
    __shared__ float sm[32][33];
    int n0 = (b & 31)*32, k0 = (b >> 5)*32;
    int t = threadIdx.x;
    int r = t >> 3, c4 = (t & 7)*4;
    *(float4*)&sm[r][c4] = *(const float4*)&W[(size_t)(k0 + r)*MCOLS + n0 + c4];
    __syncthreads();
    ushort4 h;
    h.x = f2bf(sm[c4+0][r]);
    h.y = f2bf(sm[c4+1][r]);
    h.z = f2bf(sm[c4+2][r]);
    h.w = f2bf(sm[c4+3][r]);
    *(ushort4*)&Th[(size_t)(n0 + r)*K + k0 + c4] = h;
  } else {
    int i = (b - K)*256 + threadIdx.x;
    if (i < e4) {
      int pos = i >> 2, h = i & 3;
      float v = el[srcs[pos]*HEADS + h] + er[dsts[pos]*HEADS + h];
      v = v >= 0.f ? v : 0.2f*v;
      wb[i] = __expf(v);
    }
  }
}

// ---------------- agg5 (layer 0): per-head agg of x (1KB rows) ----------------
// g0[n][h*512 + k] = (sum_e alpha_{e,h} x[src_e, k]) / den_h.  Wave per node;
// lane covers dims [lane*8, lane*8+8) (16B); one gather serves all 4 heads.
// 4-deep pipeline, next-group srcs prefetched during the 32-FMA consume phase.
__global__ __launch_bounds__(128) void k_agg5(
    const unsigned short* __restrict__ xh, const float* __restrict__ wbuf,
    const int* __restrict__ row_ptr, const int* __restrict__ srcs,
    unsigned short* __restrict__ g) {
  int t = threadIdx.x, w = t >> 6, lane = t & 63;
  int n = blockIdx.x*2 + w;
  const unsigned tb = (unsigned)(lane*16);
  if (n >= NNODES) {
    uint4 z = {0,0,0,0};
    #pragma unroll
    for (int h = 0; h < 4; ++h)
      *(uint4*)&g[(size_t)n*2048 + h*512 + lane*8] = z;
    return;
  }
  int beg = row_ptr[n], end = row_ptr[n+1];
  float den0 = 0.f, den1 = 0.f, den2 = 0.f, den3 = 0.f;
  float a0[8] = {0,0,0,0,0,0,0,0};
  float a1[8] = {0,0,0,0,0,0,0,0};
  float a2[8] = {0,0,0,0,0,0,0,0};
  float a3[8] = {0,0,0,0,0,0,0,0};
  const char* fb = (const char*)xh;

  int nfull = (end - beg) & ~3;
  int gend = beg + nfull;
  int i = beg;
  int s[4];
  if (i < gend) {
    #pragma unroll
    for (int j = 0; j < 4; ++j) s[j] = srcs[i + j];
  }
  while (i < gend) {
    float4 wv[4];
    #pragma unroll
    for (int j = 0; j < 4; ++j) wv[j] = *(const float4*)&wbuf[(size_t)(i + j)*4];
    uint4 u[4];
    #pragma unroll
    for (int j = 0; j < 4; ++j)
      u[j] = *(const uint4*)(fb + ((unsigned)s[j]*1024u + tb));
    i += 4;
    if (i < gend) {
      #pragma unroll
      for (int j = 0; j < 4; ++j) s[j] = srcs[i + j];
    }
    #pragma unroll
    for (int j = 0; j < 4; ++j) {
      den0 += wv[j].x; den1 += wv[j].y; den2 += wv[j].z; den3 += wv[j].w;
      float xv[8] = {blo(u[j].x), bhi(u[j].x), blo(u[j].y), bhi(u[j].y),
                     blo(u[j].z), bhi(u[j].z), blo(u[j].w), bhi(u[j].w)};
      #pragma unroll
      for (int d = 0; d < 8; ++d) {
        a0[d] = fmaf(wv[j].x, xv[d], a0[d]);
        a1[d] = fmaf(wv[j].y, xv[d], a1[d]);
        a2[d] = fmaf(wv[j].z, xv[d], a2[d]);
        a3[d] = fmaf(wv[j].w, xv[d], a3[d]);
      }
    }
  }
  for (; i < end; ++i) {
    int sr = srcs[i];
    float4 wv = *(const float4*)&wbuf[(size_t)i*4];
    const uint4 u = *(const uint4*)(fb + ((unsigned)sr*1024u + tb));
    den0 += wv.x; den1 += wv.y; den2 += wv.z; den3 += wv.w;
    float xv[8] = {blo(u.x), bhi(u.x), blo(u.y), bhi(u.y),
                   blo(u.z), bhi(u.z), blo(u.w), bhi(u.w)};
    #pragma unroll
    for (int d = 0; d < 8; ++d) {
      a0[d] = fmaf(wv.x, xv[d], a0[d]);
      a1[d] = fmaf(wv.y, xv[d], a1[d]);
      a2[d] = fmaf(wv.z, xv[d], a2[d]);
      a3[d] = fmaf(wv.w, xv[d], a3[d]);
    }
  }
  float i0 = den0 > 0.f ? 1.f/den0 : 0.f;
  float i1 = den1 > 0.f ? 1.f/den1 : 0.f;
  float i2 = den2 > 0.f ? 1.f/den2 : 0.f;
  float i3 = den3 > 0.f ? 1.f/den3 : 0.f;
  uint4 p;
  p.x = (unsigned)f2bf(a0[0]*i0) | ((unsigned)f2bf(a0[1]*i0) << 16);
  p.y = (unsigned)f2bf(a0[2]*i0) | ((unsigned)f2bf(a0[3]*i0) << 16);
  p.z = (unsigned)f2bf(a0[4]*i0) | ((unsigned)f2bf(a0[5]*i0) << 16);
  p.w = (unsigned)f2bf(a0[6]*i0) | ((unsigned)f2bf(a0[7]*i0) << 16);
  *(uint4*)&g[(size_t)n*2048 + 0*512 + lane*8] = p;
  p.x = (unsigned)f2bf(a1[0]*i1) | ((unsigned)f2bf(a1[1]*i1) << 16);
  p.y = (unsigned)f2bf(a1[2]*i1) | ((unsigned)f2bf(a1[3]*i1) << 16);
  p.z = (unsigned)f2bf(a1[4]*i1) | ((unsigned)f2bf(a1[5]*i1) << 16);
  p.w = (unsigned)f2bf(a1[6]*i1) | ((unsigned)f2bf(a1[7]*i1) << 16);
  *(uint4*)&g[(size_t)n*2048 + 1*512 + lane*8] = p;
  p.x = (unsigned)f2bf(a2[0]*i2) | ((unsigned)f2bf(a2[1]*i2) << 16);
  p.y = (unsigned)f2bf(a2[2]*i2) | ((unsigned)f2bf(a2[3]*i2) << 16);
  p.z = (unsigned)f2bf(a2[4]*i2) | ((unsigned)f2bf(a2[5]*i2) << 16);
  p.w = (unsigned)f2bf(a2[6]*i2) | ((unsigned)f2bf(a2[7]*i2) << 16);
  *(uint4*)&g[(size_t)n*2048 + 2*512 + lane*8] = p;
  p.x = (unsigned)f2bf(a3[0]*i3) | ((unsigned)f2bf(a3[1]*i3) << 16);
  p.y = (unsigned)f2bf(a3[2]*i3) | ((unsigned)f2bf(a3[3]*i3) << 16);
  p.z = (unsigned)f2bf(a3[4]*i3) | ((unsigned)f2bf(a3[5]*i3) << 16);
  p.w = (unsigned)f2bf(a3[6]*i3) | ((unsigned)f2bf(a3[7]*i3) << 16);
  *(uint4*)&g[(size_t)n*2048 + 3*512 + lane*8] = p;
}

// ---------------- MFMA GEMM: OUT = A @ B^T ----------------
// BD=0: A rows stride lda==K (full GEMM). BD=1: block-diagonal -- A row
// offset (bn>>1)*512 selects head's 512-wide g-slice, lda=2048, K=512.
// EPI=0: raw bf16 store (fs for l1/l2). EPI=1: +bias, relu (h1 for l0).
// XCD-aware swizzle: each XCD owns 20 exclusive bm strips.
template<int BD, int EPI>
__global__ __launch_bounds__(256, 3) void k_gemm(
    const unsigned short* __restrict__ A, const unsigned short* __restrict__ B,
    const float* __restrict__ bias, unsigned short* __restrict__ Fh,
    int K, int lda) {
  __shared__ short sAh[128*32];
  __shared__ short sBh[128*32];
  const int t = threadIdx.x;
  const int w = t >> 6, l = t & 63;
  const int b = blockIdx.x;
  const int xcd = b & 7, kk = b >> 3;
  const int bm = xcd*20 + (kk >> 3), bn = kk & 7;
  const int m0 = (w >> 1) * 64, n0 = (w & 1) * 64;

  f32x4 acc[4][4];
  #pragma unroll
  for (int i = 0; i < 4; ++i)
    #pragma unroll
    for (int j = 0; j < 4; ++j) acc[i][j] = (f32x4){0.f, 0.f, 0.f, 0.f};

  const int srow = t >> 2, koct = (t & 3) * 8;
  const size_t rA64 = (size_t)64 * lda;
  const size_t rB64 = (size_t)64 * K;
  const unsigned short* gA = A + (size_t)(bm*128 + srow)*lda
                               + (BD ? (bn >> 1)*512 : 0) + koct;
  const unsigned short* gB = B + (size_t)(bn*128 + srow)*K + koct;
  char* lA = (char*)sAh + w*1024;
  char* lB = (char*)sBh + w*1024;

  const int fr = l & 15, fq = l >> 4;

  for (int k0 = 0; k0 < K; k0 += 32) {
    async_ld16(lA,        gA + k0);
    async_ld16(lA + 4096, gA + k0 + rA64);
    async_ld16(lB,        gB + k0);
    async_ld16(lB + 4096, gB + k0 + rB64);
    __syncthreads();

    short8 bhv[4];
    #pragma unroll
    for (int nt = 0; nt < 4; ++nt)
      bhv[nt] = *(const short8*)&sBh[(n0 + nt*16 + fr)*32 + fq*8];
    #pragma unroll
    for (int mt = 0; mt < 4; ++mt) {
      int off = (m0 + mt*16 + fr)*32 + fq*8;
      short8 ah = *(const short8*)&sAh[off];
      #pragma unroll
      for (int nt = 0; nt < 4; ++nt)
        acc[mt][nt] = __builtin_amdgcn_mfma_f32_16x16x32_bf16(ah, bhv[nt], acc[mt][nt], 0, 0, 0);
    }
    __syncthreads();
  }

  #pragma unroll
  for (int nt = 0; nt < 4; ++nt) {
    const int col = bn*128 + n0 + nt*16 + fr;
    float bv = (EPI == 1) ? bias[col] : 0.f;
    #pragma unroll
    for (int mt = 0; mt < 4; ++mt) {
      size_t base = (size_t)(bm*128 + m0 + mt*16 + fq*4)*MCOLS + col;
      if (EPI == 1) {
        Fh[base          ] = f2bf(fmaxf(acc[mt][nt][0] + bv, 0.f));
        Fh[base + MCOLS  ] = f2bf(fmaxf(acc[mt][nt][1] + bv, 0.f));
        Fh[base + 2*MCOLS] = f2bf(fmaxf(acc[mt][nt][2] + bv, 0.f));
        Fh[base + 3*MCOLS] = f2bf(fmaxf(acc[mt][nt][3] + bv, 0.f));
      } else {
        Fh[base          ] = f2bf(acc[mt][nt][0]);
        Fh[base + MCOLS  ] = f2bf(acc[mt][nt][1]);
        Fh[base + 2*MCOLS] = f2bf(acc[mt][nt][2]);
        Fh[base + 3*MCOLS] = f2bf(acc[mt][nt][3]);
      }
    }
  }
}

// ---------------- fused aggregation (layer 1): r2/r5-proven flat pipeline -----
__global__ __launch_bounds__(128) void k_agg_f(
    const unsigned short* __restrict__ fsh, const float* __restrict__ wbuf,
    const int* __restrict__ row_ptr, const int* __restrict__ srcs,
    const float* __restrict__ bias,
    const float* __restrict__ WalN, const float* __restrict__ WredN,
    unsigned short* __restrict__ Ahi,
    float* __restrict__ el_next, float* __restrict__ er_next) {
  __shared__ float red_sm[2][8];
  int n = blockIdx.x;
  int t = threadIdx.x;
  int w = t >> 6, lane = t & 63;
  int half = lane >> 5, lam = lane & 31;
  int head = w*2 + half;
  int k0 = head*DDIM + lam*8;
  if (n >= NNODES) {
    uint4 z = {0,0,0,0};
    *(uint4*)&Ahi[(size_t)n*MCOLS + k0] = z;
    return;
  }
  int beg = row_ptr[n], end = row_ptr[n+1];
  float den = 0.f;
  float ac[8];
  #pragma unroll
  for (int j = 0; j < 8; ++j) ac[j] = 0.f;
  const char* fbyte = (const char*)fsh;
  const unsigned tb = (unsigned)(k0*2);

  int nfull = (end - beg) & ~7;
  int gend = beg + nfull;
  int i = beg;
  int s[8];
  if (i < gend) {
    #pragma unroll
    for (int j = 0; j < 8; ++j) s[j] = srcs[i + j];
  }
  while (i < gend) {
    float wg[8];
    #pragma unroll
    for (int j = 0; j < 8; ++j) {
      float2 wv = *(const float2*)&wbuf[(size_t)(i + j)*HEADS + w*2];
      wg[j] = half ? wv.y : wv.x;
    }
    uint4 u[8];
    #pragma unroll
    for (int j = 0; j < 8; ++j)
      u[j] = *(const uint4*)(fbyte + ((unsigned)s[j]*2048u + tb));
    i += 8;
    if (i < gend) {
      #pragma unroll
      for (int j = 0; j < 8; ++j) s[j] = srcs[i + j];
    }
    #pragma unroll
    for (int j = 0; j < 8; ++j) {
      den += wg[j];
      ac[0] = fmaf(wg[j], blo(u[j].x), ac[0]);
      ac[1] = fmaf(wg[j], bhi(u[j].x), ac[1]);
      ac[2] = fmaf(wg[j], blo(u[j].y), ac[2]);
      ac[3] = fmaf(wg[j], bhi(u[j].y), ac[3]);
      ac[4] = fmaf(wg[j], blo(u[j].z), ac[4]);
      ac[5] = fmaf(wg[j], bhi(u[j].z), ac[5]);
      ac[6] = fmaf(wg[j], blo(u[j].w), ac[6]);
      ac[7] = fmaf(wg[j], bhi(u[j].w), ac[7]);
    }
  }
  for (; i < end; ++i) {
    int sr = srcs[i];
    float2 wv = *(const float2*)&wbuf[(size_t)i*HEADS + w*2];
    float wgt = half ? wv.y : wv.x;
    const uint4 u = *(const uint4*)(fbyte + ((unsigned)sr*2048u + tb));
    den += wgt;
    ac[0] = fmaf(wgt, blo(u.x), ac[0]);
    ac[1] = fmaf(wgt, bhi(u.x), ac[1]);
    ac[2] = fmaf(wgt, blo(u.y), ac[2]);
    ac[3] = fmaf(wgt, bhi(u.y), ac[3]);
    ac[4] = fmaf(wgt, blo(u.z), ac[4]);
    ac[5] = fmaf(wgt, bhi(u.z), ac[5]);
    ac[6] = fmaf(wgt, blo(u.w), ac[6]);
    ac[7] = fmaf(wgt, bhi(u.w), ac[7]);
  }
  float inv = den > 0.f ? 1.f/den : 0.f;
  const float4 bv0 = *(const float4*)&bias[k0];
  const float4 bv1 = *(const float4*)&bias[k0 + 4];
  float o[8];
  o[0] = fmaxf(ac[0]*inv + bv0.x, 0.f);
  o[1] = fmaxf(ac[1]*inv + bv0.y, 0.f);
  o[2] = fmaxf(ac[2]*inv + bv0.z, 0.f);
  o[3] = fmaxf(ac[3]*inv + bv0.w, 0.f);
  o[4] = fmaxf(ac[4]*inv + bv1.x, 0.f);
  o[5] = fmaxf(ac[5]*inv + bv1.y, 0.f);
  o[6] = fmaxf(ac[6]*inv + bv1.z, 0.f);
  o[7] = fmaxf(ac[7]*inv + bv1.w, 0.f);
  uint4 hp;
  hp.x = (unsigned)f2bf(o[0]) | ((unsigned)f2bf(o[1]) << 16);
  hp.y = (unsigned)f2bf(o[2]) | ((unsigned)f2bf(o[3]) << 16);
  hp.z = (unsigned)f2bf(o[4]) | ((unsigned)f2bf(o[5]) << 16);
  hp.w = (unsigned)f2bf(o[6]) | ((unsigned)f2bf(o[7]) << 16);
  *(uint4*)&Ahi[(size_t)n*MCOLS + k0] = hp;
  // el/er next
  float p[8];
  #pragma unroll
  for (int j = 0; j < 8; ++j) p[j] = 0.f;
  #pragma unroll
  for (int j = 0; j < 8; ++j) {
    const float4 wa = *(const float4*)&WalN[(k0+j)*HEADS];
    const float4 wr = *(const float4*)&WredN[(k0+j)*HEADS];
    p[0] = fmaf(o[j], wa.x, p[0]);
    p[1] = fmaf(o[j], wa.y, p[1]);
    p[2] = fmaf(o[j], wa.z, p[2]);
    p[3] = fmaf(o[j], wa.w, p[3]);
    p[4] = fmaf(o[j], wr.x, p[4]);
    p[5] = fmaf(o[j], wr.y, p[5]);
    p[6] = fmaf(o[j], wr.z, p[6]);
    p[7] = fmaf(o[j], wr.w, p[7]);
  }
  for (int off = 32; off; off >>= 1)
    #pragma unroll
    for (int j = 0; j < 8; ++j) p[j] += __shfl_xor(p[j], off);
  if (lane == 0)
    #pragma unroll
    for (int j = 0; j < 8; ++j) red_sm[w][j] = p[j];
  __syncthreads();
  if (t < 8) {
    float v = red_sm[0][t] + red_sm[1][t];
    if (t < 4) el_next[n*HEADS + t] = v;
    else       er_next[n*HEADS + (t-4)] = v;
  }
}

// ---------------- final aggregation (layer 2): r5-proven flat pipeline -------
__global__ __launch_bounds__(128) void k_agg_out(
    const unsigned short* __restrict__ fsh, const float* __restrict__ wbuf,
    const int* __restrict__ row_ptr, const int* __restrict__ srcs,
    const float* __restrict__ bias, float* __restrict__ out) {
  __shared__ float sm[HEADS*DDIM];
  int n = blockIdx.x;
  int t = threadIdx.x;
  int w = t >> 6, lane = t & 63;
  int half = lane >> 5, lam = lane & 31;
  int head = w*2 + half;
  int k0 = head*DDIM + lam*8;
  int beg = row_ptr[n], end = row_ptr[n+1];
  float den = 0.f;
  float ac[8];
  #pragma unroll
  for (int j = 0; j < 8; ++j) ac[j] = 0.f;
  const char* fbyte = (const char*)fsh;
  const unsigned tb = (unsigned)(k0*2);

  int nfull = (end - beg) & ~7;
  int gend = beg + nfull;
  int i = beg;
  int s[8];
  if (i < gend) {
    #pragma unroll
    for (int j = 0; j < 8; ++j) s[j] = srcs[i + j];
  }
  while (i < gend) {
    float wg[8];
    #pragma unroll
    for (int j = 0; j < 8; ++j) {
      float2 wv = *(const float2*)&wbuf[(size_t)(i + j)*HEADS + w*2];
      wg[j] = half ? wv.y : wv.x;
    }
    uint4 u[8];
    #pragma unroll
    for (int j = 0; j < 8; ++j)
      u[j] = *(const uint4*)(fbyte + ((unsigned)s[j]*2048u + tb));
    i += 8;
    if (i < gend) {
      #pragma unroll
      for (int j = 0; j < 8; ++j) s[j] = srcs[i + j];
    }
    #pragma unroll
    for (int j = 0; j < 8; ++j) {
      den += wg[j];
      ac[0] = fmaf(wg[j], blo(u[j].x), ac[0]);
      ac[1] = fmaf(wg[j], bhi(u[j].x), ac[1]);
      ac[2] = fmaf(wg[j], blo(u[j].y), ac[2]);
      ac[3] = fmaf(wg[j], bhi(u[j].y), ac[3]);
      ac[4] = fmaf(wg[j], blo(u[j].z), ac[4]);
      ac[5] = fmaf(wg[j], bhi(u[j].z), ac[5]);
      ac[6] = fmaf(wg[j], blo(u[j].w), ac[6]);
      ac[7] = fmaf(wg[j], bhi(u[j].w), ac[7]);
    }
  }
  for (; i < end; ++i) {
    int sr = srcs[i];
    float2 wv = *(const float2*)&wbuf[(size_t)i*HEADS + w*2];
    float wgt = half ? wv.y : wv.x;
    const uint4 u = *(const uint4*)(fbyte + ((unsigned)sr*2048u + tb));
    den += wgt;
    ac[0] = fmaf(wgt, blo(u.x), ac[0]);
    ac[1] = fmaf(wgt, bhi(u.x), ac[1]);
    ac[2] = fmaf(wgt, blo(u.y), ac[2]);
    ac[3] = fmaf(wgt, bhi(u.y), ac[3]);
    ac[4] = fmaf(wgt, blo(u.z), ac[4]);
    ac[5] = fmaf(wgt, bhi(u.z), ac[5]);
    ac[6] = fmaf(wgt, blo(u.w), ac[6]);
    ac[7] = fmaf(wgt, bhi(u.w), ac[7]);
  }
  float inv = den > 0.f ? 1.f/den : 0.f;
  const float4 bv0 = *(const float4*)&bias[k0];
  const float4 bv1 = *(const float4*)&bias[k0 + 4];
  sm[k0+0] = ac[0]*inv + bv0.x;
  sm[k0+1] = ac[1]*inv + bv0.y;
  sm[k0+2] = ac[2]*inv + bv0.z;
  sm[k0+3] = ac[3]*inv + bv0.w;
  sm[k0+4] = ac[4]*inv + bv1.x;
  sm[k0+5] = ac[5]*inv + bv1.y;
  sm[k0+6] = ac[6]*inv + bv1.z;
  sm[k0+7] = ac[7]*inv + bv1.w;
  __syncthreads();
  #pragma unroll
  for (int rep = 0; rep < 2; ++rep) {
    int d = t + rep*128;
    out[(size_t)n*DDIM + d] =
        0.25f*((sm[d] + sm[DDIM + d]) + (sm[2*DDIM + d] + sm[3*DDIM + d]));
  }
}

extern "C" void kernel_launch(void* const* d_in, const int* in_sizes, int n_in,
                              void* d_out, int out_size, void* d_ws, size_t ws_size,
                              hipStream_t stream) {
  const float* x   = (const float*)d_in[0];
  const int*   src = (const int*)d_in[1];
  const int*   dst = (const int*)d_in[2];
  const float* Wsrc[3] = {(const float*)d_in[3], (const float*)d_in[8],  (const float*)d_in[13]};
  const float* Wdst[3] = {(const float*)d_in[4], (const float*)d_in[9],  (const float*)d_in[14]};
  const float* al[3]   = {(const float*)d_in[5], (const float*)d_in[10], (const float*)d_in[15]};
  const float* ar[3]   = {(const float*)d_in[6], (const float*)d_in[11], (const float*)d_in[16]};
  const float* bb[3]   = {(const float*)d_in[7], (const float*)d_in[12], (const float*)d_in[17]};

  char* ws = (char*)d_ws;
  size_t off = 0;
  auto alloc = [&](size_t bytes) { void* p = ws + off; off += (bytes + 255) & ~255ull; return p; };
  unsigned short* xh   = (unsigned short*)alloc((size_t)NPAD*512*2);    // x bf16
  unsigned short* gbuf = (unsigned short*)alloc((size_t)NPAD*2048*2);   // g0 [N][H*512]
  unsigned short* hbuf = (unsigned short*)alloc((size_t)NPAD*MCOLS*2);  // h1 / h2
  unsigned short* fshB = (unsigned short*)alloc((size_t)NPAD*MCOLS*2);  // fs1 / fs2
  unsigned short* Wth  = (unsigned short*)alloc((size_t)MCOLS*MCOLS*2);
  float* elA  = (float*)alloc((size_t)NNODES*HEADS*4);
  float* elB  = (float*)alloc((size_t)NNODES*HEADS*4);
  float* erA  = (float*)alloc((size_t)NNODES*HEADS*4);
  float* erB  = (float*)alloc((size_t)NNODES*HEADS*4);
  float* wbuf = (float*)alloc((size_t)NEDGES*HEADS*4);
  float* WredB[3]; float* WalB[3];
  for (int l = 0; l < 3; ++l) {
    WredB[l] = (float*)alloc(1024*HEADS*4);
    WalB[l]  = (float*)alloc(1024*HEADS*4);
  }
  int* deg     = (int*)alloc((size_t)NNODES*4);
  int* row_ptr = (int*)alloc((size_t)(NNODES+1)*4);
  int* cursor  = (int*)alloc((size_t)NNODES*4);
  int* srcs    = (int*)alloc((size_t)NEDGES*4);
  int* dsts    = (int*)alloc((size_t)NEDGES*4);
  (void)ws_size; (void)in_sizes; (void)n_in; (void)out_size;

  // CSR build
  k_zero<<<(NNODES+255)/256, 256, 0, stream>>>(deg, NNODES);
  k_hist<<<(NEDGES+255)/256, 256, 0, stream>>>(dst, deg, NEDGES);
  k_scan<<<1, 1024, 0, stream>>>(deg, row_ptr, cursor);
  k_fill<<<(NEDGES+255)/256, 256, 0, stream>>>(src, dst, cursor, srcs, dsts, NEDGES);

  // folds
  k_fold_all<<<5120, 256, 0, stream>>>(
      Wdst[0], ar[0], WredB[0], Wsrc[0], al[0], WalB[0],
      Wdst[1], ar[1], WredB[1], Wsrc[1], al[1], WalB[1],
      Wdst[2], ar[2], WredB[2], Wsrc[2], al[2], WalB[2]);

  // x -> bf16 table + el0/er0
  k_prep0<<<NPAD, 256, 0, stream>>>(x, WalB[0], WredB[0], xh, elA, erA);

  const int E4 = NEDGES*HEADS;

  // ---- layer 0: wgt -> per-head agg(x) -> block-diagonal GEMM -> h1 ----
  k_cvtw_wgt<<<512 + (E4 + 255)/256, 256, 0, stream>>>(
      Wsrc[0], Wth, 512, elA, erA, srcs, dsts, wbuf, E4);
  k_agg5<<<NPAD/2, 128, 0, stream>>>(xh, wbuf, row_ptr, srcs, gbuf);
  k_gemm<1, 1><<<NBM*8, 256, 0, stream>>>(gbuf, Wth, bb[0], hbuf, 512, 2048);
  k_elr<<<NNODES, 256, 0, stream>>>(hbuf, WalB[1], WredB[1], elB, erB);

  // ---- layer 1: wgt -> GEMM(h1) -> fs1 -> agg (+el2/er2) -> h2 ----
  k_cvtw_wgt<<<1024 + (E4 + 255)/256, 256, 0, stream>>>(
      Wsrc[1], Wth, 1024, elB, erB, srcs, dsts, wbuf, E4);
  k_gemm<0, 0><<<NBM*8, 256, 0, stream>>>(hbuf, Wth, nullptr, fshB, 1024, 1024);
  k_agg_f<<<NPAD, 128, 0, stream>>>(fshB, wbuf, row_ptr, srcs, bb[1],
                                    WalB[2], WredB[2], hbuf, elA, erA);

  // ---- layer 2: wgt -> GEMM(h2) -> fs2 -> agg_out (head mean) -> out ----
  k_cvtw_wgt<<<1024 + (E4 + 255)/256, 256, 0, stream>>>(
      Wsrc[2], Wth, 1024, elA, erA, srcs, dsts, wbuf, E4);
  k_gemm<0, 0><<<NBM*8, 256, 0, stream>>>(hbuf, Wth, nullptr, fshB, 1024, 1024);
  k_agg_out<<<NNODES, 128, 0, stream>>>(fshB, wbuf, row_ptr, srcs, bb[2],
                                        (float*)d_out);
}

// Round 11
// 701.291 us; speedup vs baseline: 1.9407x; 1.0061x over previous
//
#include <hip/hip_runtime.h>
#include <hip/hip_bf16.h>
#include <math.h>

#define NNODES 20000
#define NPAD   20480   // 160 * 128
#define NBM    160
#define NEDGES 320000
#define HEADS  4
#define DDIM   256
#define MCOLS  1024   // H*D

typedef __attribute__((ext_vector_type(8))) short short8;
typedef __attribute__((ext_vector_type(4))) float f32x4;

// bf16 helpers (bit-level, RNE)
__device__ __forceinline__ unsigned short f2bf(float f) {
  unsigned u = __float_as_uint(f);
  unsigned r = (u + 0x7fffu + ((u >> 16) & 1u)) >> 16;
  return (unsigned short)r;
}
__device__ __forceinline__ float bf2f(unsigned short h) {
  return __uint_as_float(((unsigned)h) << 16);
}
__device__ __forceinline__ float blo(unsigned v) { return __uint_as_float(v << 16); }
__device__ __forceinline__ float bhi(unsigned v) { return __uint_as_float(v & 0xffff0000u); }

__device__ __forceinline__ void async_ld16(void* lds, const void* g) {
  __builtin_amdgcn_global_load_lds(
      (const __attribute__((address_space(1))) unsigned int*)g,
      (__attribute__((address_space(3))) unsigned int*)lds, 16, 0, 0);
}

// ---------------- CSR build (by dst) ----------------
__global__ void k_hist(const int* __restrict__ dst, int* deg, int e) {
  int i = blockIdx.x*blockDim.x + threadIdx.x;
  if (i < e) atomicAdd(&deg[dst[i]], 1);
}
__global__ void k_scan(const int* __restrict__ deg, int* row_ptr, int* cursor) {
  __shared__ int sm[1024];
  int t = threadIdx.x;
  const int CH = 20;
  int base = t*CH;
  int s = 0;
  #pragma unroll
  for (int i = 0; i < CH; ++i) { int idx = base+i; if (idx < NNODES) s += deg[idx]; }
  int val = s;
  sm[t] = s; __syncthreads();
  for (int off = 1; off < 1024; off <<= 1) {
    int add = (t >= off) ? sm[t-off] : 0;
    __syncthreads();
    val += add; sm[t] = val;
    __syncthreads();
  }
  int run = val - s;
  for (int i = 0; i < CH; ++i) {
    int idx = base+i;
    if (idx < NNODES) { row_ptr[idx] = run; cursor[idx] = run; run += deg[idx]; }
  }
  if (t == 0) row_ptr[NNODES] = NEDGES;
}
__global__ void k_fill(const int* __restrict__ src, const int* __restrict__ dst,
                       int* cursor, int* srcs_sorted, int* dsts_sorted, int e) {
  int i = blockIdx.x*blockDim.x + threadIdx.x;
  if (i < e) {
    int d = dst[i];
    int pos = atomicAdd(&cursor[d], 1);
    srcs_sorted[pos] = src[i];
    dsts_sorted[pos] = d;
  }
}

// ---------------- folds + ALL THREE W-transposes in one launch ----------------
__device__ __forceinline__ void fold_body(const float* __restrict__ W,
                                          const float* __restrict__ v,
                                          float* __restrict__ F, int K, int bb) {
  int wave = threadIdx.x >> 6, lane = threadIdx.x & 63;
  int p = bb*4 + wave;            // p < K*4
  int k = p >> 2, h = p & 3;
  const float4 wv = *(const float4*)&W[(size_t)k*MCOLS + h*DDIM + lane*4];
  const float4 av = *(const float4*)&v[h*DDIM + lane*4];
  float s = wv.x*av.x + wv.y*av.y + wv.z*av.z + wv.w*av.w;
  for (int off = 32; off; off >>= 1) s += __shfl_xor(s, off);
  if (lane == 0) F[k*HEADS + h] = s;
}
__global__ __launch_bounds__(256) void k_fold_cvt_all(
    const float* Wd0, const float* ar0, float* F0,
    const float* Ws0, const float* al0, float* G0,
    const float* Wd1, const float* ar1, float* F1,
    const float* Ws1, const float* al1, float* G1,
    const float* Wd2, const float* ar2, float* F2,
    const float* Ws2, const float* al2, float* G2,
    unsigned short* Th0, unsigned short* Th1, unsigned short* Th2) {
  int b = blockIdx.x;
  if (b < 5120) {
    if      (b < 512)  fold_body(Wd0, ar0, F0, 512,  b);
    else if (b < 1024) fold_body(Ws0, al0, G0, 512,  b - 512);
    else if (b < 2048) fold_body(Wd1, ar1, F1, 1024, b - 1024);
    else if (b < 3072) fold_body(Ws1, al1, G1, 1024, b - 2048);
    else if (b < 4096) fold_body(Wd2, ar2, F2, 1024, b - 3072);
    else               fold_body(Ws2, al2, G2, 1024, b - 4096);
    return;
  }
  // transpose part: Th[n][k] = bf16(W[k][n]), n<1024
  b -= 5120;
  const float* W; unsigned short* Th; int K;
  if (b < 512)       { W = Ws0; Th = Th0; K = 512; }
  else if (b < 1536) { W = Ws1; Th = Th1; K = 1024; b -= 512; }
  else               { W = Ws2; Th = Th2; K = 1024; b -= 1536; }
  __shared__ float sm[32][33];
  int n0 = (b & 31)*32, k0 = (b >> 5)*32;
  int t = threadIdx.x;
  int r = t >> 3, c4 = (t & 7)*4;
  *(float4*)&sm[r][c4] = *(const float4*)&W[(size_t)(k0 + r)*MCOLS + n0 + c4];
  __syncthreads();
  ushort4 h;
  h.x = f2bf(sm[c4+0][r]);
  h.y = f2bf(sm[c4+1][r]);
  h.z = f2bf(sm[c4+2][r]);
  h.w = f2bf(sm[c4+3][r]);
  *(ushort4*)&Th[(size_t)(n0 + r)*K + k0 + c4] = h;
}

// ---------------- layer-0 prep: x -> bf16 table + el0/er0 ----------------
__global__ __launch_bounds__(256) void k_prep0(
    const float* __restrict__ x, const float* __restrict__ Wal,
    const float* __restrict__ Wred,
    unsigned short* __restrict__ xh,
    float* __restrict__ el, float* __restrict__ er) {
  __shared__ float red_sm[4][8];
  int n = blockIdx.x, t = threadIdx.x;
  if (n >= NNODES) {
    *(ushort2*)&xh[(size_t)n*512 + 2*t] = (ushort2){0,0};
    return;
  }
  float2 xv = *(const float2*)&x[(size_t)n*512 + 2*t];
  ushort2 h2;
  h2.x = f2bf(xv.x);
  h2.y = f2bf(xv.y);
  *(ushort2*)&xh[(size_t)n*512 + 2*t] = h2;
  const float4 wa0 = *(const float4*)&Wal[(2*t)*4];
  const float4 wa1 = *(const float4*)&Wal[(2*t+1)*4];
  const float4 wr0 = *(const float4*)&Wred[(2*t)*4];
  const float4 wr1 = *(const float4*)&Wred[(2*t+1)*4];
  float p[8];
  p[0] = xv.x*wa0.x + xv.y*wa1.x;
  p[1] = xv.x*wa0.y + xv.y*wa1.y;
  p[2] = xv.x*wa0.z + xv.y*wa1.z;
  p[3] = xv.x*wa0.w + xv.y*wa1.w;
  p[4] = xv.x*wr0.x + xv.y*wr1.x;
  p[5] = xv.x*wr0.y + xv.y*wr1.y;
  p[6] = xv.x*wr0.z + xv.y*wr1.z;
  p[7] = xv.x*wr0.w + xv.y*wr1.w;
  for (int off = 32; off; off >>= 1)
    #pragma unroll
    for (int j = 0; j < 8; ++j) p[j] += __shfl_xor(p[j], off);
  if ((t & 63) == 0)
    #pragma unroll
    for (int j = 0; j < 8; ++j) red_sm[t >> 6][j] = p[j];
  __syncthreads();
  if (t < 8) {
    float v = (red_sm[0][t] + red_sm[1][t]) + (red_sm[2][t] + red_sm[3][t]);
    if (t < 4) el[n*HEADS + t] = v;
    else       er[n*HEADS + (t-4)] = v;
  }
}

// ---------------- el/er for next layer from h (bf16, 1024-wide) ----------------
__global__ __launch_bounds__(256) void k_elr(
    const unsigned short* __restrict__ h, const float* __restrict__ Wal,
    const float* __restrict__ Wred,
    float* __restrict__ el, float* __restrict__ er) {
  __shared__ float red_sm[4][8];
  int n = blockIdx.x, t = threadIdx.x;
  ushort4 hv = *(const ushort4*)&h[(size_t)n*MCOLS + 4*t];
  float xv[4] = {bf2f(hv.x), bf2f(hv.y), bf2f(hv.z), bf2f(hv.w)};
  float p[8] = {0.f,0.f,0.f,0.f,0.f,0.f,0.f,0.f};
  #pragma unroll
  for (int j = 0; j < 4; ++j) {
    const float4 wa = *(const float4*)&Wal[(4*t + j)*HEADS];
    const float4 wr = *(const float4*)&Wred[(4*t + j)*HEADS];
    p[0] = fmaf(xv[j], wa.x, p[0]);
    p[1] = fmaf(xv[j], wa.y, p[1]);
    p[2] = fmaf(xv[j], wa.z, p[2]);
    p[3] = fmaf(xv[j], wa.w, p[3]);
    p[4] = fmaf(xv[j], wr.x, p[4]);
    p[5] = fmaf(xv[j], wr.y, p[5]);
    p[6] = fmaf(xv[j], wr.z, p[6]);
    p[7] = fmaf(xv[j], wr.w, p[7]);
  }
  for (int off = 32; off; off >>= 1)
    #pragma unroll
    for (int j = 0; j < 8; ++j) p[j] += __shfl_xor(p[j], off);
  if ((t & 63) == 0)
    #pragma unroll
    for (int j = 0; j < 8; ++j) red_sm[t >> 6][j] = p[j];
  __syncthreads();
  if (t < 8) {
    float v = (red_sm[0][t] + red_sm[1][t]) + (red_sm[2][t] + red_sm[3][t]);
    if (t < 4) el[n*HEADS + t] = v;
    else       er[n*HEADS + (t-4)] = v;
  }
}

// ---------------- per-edge softmax weights: 1 thread/edge, float4 I/O ----------
// wb interleaved: wb[pos*4 + h] (unchanged layout, identical numerics).
__global__ __launch_bounds__(256) void k_wgt_e(
    const float* __restrict__ el, const float* __restrict__ er,
    const int* __restrict__ srcs, const int* __restrict__ dsts,
    float* __restrict__ wb, int e) {
  int i = blockIdx.x*256 + threadIdx.x;
  if (i < e) {
    const float4 a = *(const float4*)&el[srcs[i]*HEADS];
    const float4 b = *(const float4*)&er[dsts[i]*HEADS];
    float4 v;
    v.x = a.x + b.x; v.x = v.x >= 0.f ? v.x : 0.2f*v.x; v.x = __expf(v.x);
    v.y = a.y + b.y; v.y = v.y >= 0.f ? v.y : 0.2f*v.y; v.y = __expf(v.y);
    v.z = a.z + b.z; v.z = v.z >= 0.f ? v.z : 0.2f*v.z; v.z = __expf(v.z);
    v.w = a.w + b.w; v.w = v.w >= 0.f ? v.w : 0.2f*v.w; v.w = __expf(v.w);
    *(float4*)&wb[(size_t)i*4] = v;
  }
}

// ---------------- agg5 (layer 0): per-head agg of x (1KB rows) ----------------
__global__ __launch_bounds__(128) void k_agg5(
    const unsigned short* __restrict__ xh, const float* __restrict__ wbuf,
    const int* __restrict__ row_ptr, const int* __restrict__ srcs,
    unsigned short* __restrict__ g) {
  int t = threadIdx.x, w = t >> 6, lane = t & 63;
  int n = blockIdx.x*2 + w;
  const unsigned tb = (unsigned)(lane*16);
  if (n >= NNODES) {
    uint4 z = {0,0,0,0};
    #pragma unroll
    for (int h = 0; h < 4; ++h)
      *(uint4*)&g[(size_t)n*2048 + h*512 + lane*8] = z;
    return;
  }
  int beg = row_ptr[n], end = row_ptr[n+1];
  float den0 = 0.f, den1 = 0.f, den2 = 0.f, den3 = 0.f;
  float a0[8] = {0,0,0,0,0,0,0,0};
  float a1[8] = {0,0,0,0,0,0,0,0};
  float a2[8] = {0,0,0,0,0,0,0,0};
  float a3[8] = {0,0,0,0,0,0,0,0};
  const char* fb = (const char*)xh;

  int nfull = (end - beg) & ~3;
  int gend = beg + nfull;
  int i = beg;
  int s[4];
  if (i < gend) {
    #pragma unroll
    for (int j = 0; j < 4; ++j) s[j] = srcs[i + j];
  }
  while (i < gend) {
    float4 wv[4];
    #pragma unroll
    for (int j = 0; j < 4; ++j) wv[j] = *(const float4*)&wbuf[(size_t)(i + j)*4];
    uint4 u[4];
    #pragma unroll
    for (int j = 0; j < 4; ++j)
      u[j] = *(const uint4*)(fb + ((unsigned)s[j]*1024u + tb));
    i += 4;
    if (i < gend) {
      #pragma unroll
      for (int j = 0; j < 4; ++j) s[j] = srcs[i + j];
    }
    #pragma unroll
    for (int j = 0; j < 4; ++j) {
      den0 += wv[j].x; den1 += wv[j].y; den2 += wv[j].z; den3 += wv[j].w;
      float xv[8] = {blo(u[j].x), bhi(u[j].x), blo(u[j].y), bhi(u[j].y),
                     blo(u[j].z), bhi(u[j].z), blo(u[j].w), bhi(u[j].w)};
      #pragma unroll
      for (int d = 0; d < 8; ++d) {
        a0[d] = fmaf(wv[j].x, xv[d], a0[d]);
        a1[d] = fmaf(wv[j].y, xv[d], a1[d]);
        a2[d] = fmaf(wv[j].z, xv[d], a2[d]);
        a3[d] = fmaf(wv[j].w, xv[d], a3[d]);
      }
    }
  }
  for (; i < end; ++i) {
    int sr = srcs[i];
    float4 wv = *(const float4*)&wbuf[(size_t)i*4];
    const uint4 u = *(const uint4*)(fb + ((unsigned)sr*1024u + tb));
    den0 += wv.x; den1 += wv.y; den2 += wv.z; den3 += wv.w;
    float xv[8] = {blo(u.x), bhi(u.x), blo(u.y), bhi(u.y),
                   blo(u.z), bhi(u.z), blo(u.w), bhi(u.w)};
    #pragma unroll
    for (int d = 0; d < 8; ++d) {
      a0[d] = fmaf(wv.x, xv[d], a0[d]);
      a1[d] = fmaf(wv.y, xv[d], a1[d]);
      a2[d] = fmaf(wv.z, xv[d], a2[d]);
      a3[d] = fmaf(wv.w, xv[d], a3[d]);
    }
  }
  float i0 = den0 > 0.f ? 1.f/den0 : 0.f;
  float i1 = den1 > 0.f ? 1.f/den1 : 0.f;
  float i2 = den2 > 0.f ? 1.f/den2 : 0.f;
  float i3 = den3 > 0.f ? 1.f/den3 : 0.f;
  uint4 p;
  p.x = (unsigned)f2bf(a0[0]*i0) | ((unsigned)f2bf(a0[1]*i0) << 16);
  p.y = (unsigned)f2bf(a0[2]*i0) | ((unsigned)f2bf(a0[3]*i0) << 16);
  p.z = (unsigned)f2bf(a0[4]*i0) | ((unsigned)f2bf(a0[5]*i0) << 16);
  p.w = (unsigned)f2bf(a0[6]*i0) | ((unsigned)f2bf(a0[7]*i0) << 16);
  *(uint4*)&g[(size_t)n*2048 + 0*512 + lane*8] = p;
  p.x = (unsigned)f2bf(a1[0]*i1) | ((unsigned)f2bf(a1[1]*i1) << 16);
  p.y = (unsigned)f2bf(a1[2]*i1) | ((unsigned)f2bf(a1[3]*i1) << 16);
  p.z = (unsigned)f2bf(a1[4]*i1) | ((unsigned)f2bf(a1[5]*i1) << 16);
  p.w = (unsigned)f2bf(a1[6]*i1) | ((unsigned)f2bf(a1[7]*i1) << 16);
  *(uint4*)&g[(size_t)n*2048 + 1*512 + lane*8] = p;
  p.x = (unsigned)f2bf(a2[0]*i2) | ((unsigned)f2bf(a2[1]*i2) << 16);
  p.y = (unsigned)f2bf(a2[2]*i2) | ((unsigned)f2bf(a2[3]*i2) << 16);
  p.z = (unsigned)f2bf(a2[4]*i2) | ((unsigned)f2bf(a2[5]*i2) << 16);
  p.w = (unsigned)f2bf(a2[6]*i2) | ((unsigned)f2bf(a2[7]*i2) << 16);
  *(uint4*)&g[(size_t)n*2048 + 2*512 + lane*8] = p;
  p.x = (unsigned)f2bf(a3[0]*i3) | ((unsigned)f2bf(a3[1]*i3) << 16);
  p.y = (unsigned)f2bf(a3[2]*i3) | ((unsigned)f2bf(a3[3]*i3) << 16);
  p.z = (unsigned)f2bf(a3[4]*i3) | ((unsigned)f2bf(a3[5]*i3) << 16);
  p.w = (unsigned)f2bf(a3[6]*i3) | ((unsigned)f2bf(a3[7]*i3) << 16);
  *(uint4*)&g[(size_t)n*2048 + 3*512 + lane*8] = p;
}

// ---------------- MFMA GEMM: OUT = A @ B^T ----------------
// BD=0: lda==K. BD=1: block-diagonal (head = bn>>1, A offset (bn>>1)*512).
// EPI=0: raw bf16 store. EPI=1: +bias, relu.
template<int BD, int EPI>
__global__ __launch_bounds__(256, 3) void k_gemm(
    const unsigned short* __restrict__ A, const unsigned short* __restrict__ B,
    const float* __restrict__ bias, unsigned short* __restrict__ Fh,
    int K, int lda) {
  __shared__ short sAh[128*32];
  __shared__ short sBh[128*32];
  const int t = threadIdx.x;
  const int w = t >> 6, l = t & 63;
  const int b = blockIdx.x;
  const int xcd = b & 7, kk = b >> 3;
  const int bm = xcd*20 + (kk >> 3), bn = kk & 7;
  const int m0 = (w >> 1) * 64, n0 = (w & 1) * 64;

  f32x4 acc[4][4];
  #pragma unroll
  for (int i = 0; i < 4; ++i)
    #pragma unroll
    for (int j = 0; j < 4; ++j) acc[i][j] = (f32x4){0.f, 0.f, 0.f, 0.f};

  const int srow = t >> 2, koct = (t & 3) * 8;
  const size_t rA64 = (size_t)64 * lda;
  const size_t rB64 = (size_t)64 * K;
  const unsigned short* gA = A + (size_t)(bm*128 + srow)*lda
                               + (BD ? (bn >> 1)*512 : 0) + koct;
  const unsigned short* gB = B + (size_t)(bn*128 + srow)*K + koct;
  char* lA = (char*)sAh + w*1024;
  char* lB = (char*)sBh + w*1024;

  const int fr = l & 15, fq = l >> 4;

  for (int k0 = 0; k0 < K; k0 += 32) {
    async_ld16(lA,        gA + k0);
    async_ld16(lA + 4096, gA + k0 + rA64);
    async_ld16(lB,        gB + k0);
    async_ld16(lB + 4096, gB + k0 + rB64);
    __syncthreads();

    short8 bhv[4];
    #pragma unroll
    for (int nt = 0; nt < 4; ++nt)
      bhv[nt] = *(const short8*)&sBh[(n0 + nt*16 + fr)*32 + fq*8];
    #pragma unroll
    for (int mt = 0; mt < 4; ++mt) {
      int off = (m0 + mt*16 + fr)*32 + fq*8;
      short8 ah = *(const short8*)&sAh[off];
      #pragma unroll
      for (int nt = 0; nt < 4; ++nt)
        acc[mt][nt] = __builtin_amdgcn_mfma_f32_16x16x32_bf16(ah, bhv[nt], acc[mt][nt], 0, 0, 0);
    }
    __syncthreads();
  }

  #pragma unroll
  for (int nt = 0; nt < 4; ++nt) {
    const int col = bn*128 + n0 + nt*16 + fr;
    float bv = (EPI == 1) ? bias[col] : 0.f;
    #pragma unroll
    for (int mt = 0; mt < 4; ++mt) {
      size_t base = (size_t)(bm*128 + m0 + mt*16 + fq*4)*MCOLS + col;
      if (EPI == 1) {
        Fh[base          ] = f2bf(fmaxf(acc[mt][nt][0] + bv, 0.f));
        Fh[base + MCOLS  ] = f2bf(fmaxf(acc[mt][nt][1] + bv, 0.f));
        Fh[base + 2*MCOLS] = f2bf(fmaxf(acc[mt][nt][2] + bv, 0.f));
        Fh[base + 3*MCOLS] = f2bf(fmaxf(acc[mt][nt][3] + bv, 0.f));
      } else {
        Fh[base          ] = f2bf(acc[mt][nt][0]);
        Fh[base + MCOLS  ] = f2bf(acc[mt][nt][1]);
        Fh[base + 2*MCOLS] = f2bf(acc[mt][nt][2]);
        Fh[base + 3*MCOLS] = f2bf(acc[mt][nt][3]);
      }
    }
  }
}

// ---------------- fused aggregation (layer 1): flat 8-deep pipeline ----------
__global__ __launch_bounds__(128) void k_agg_f(
    const unsigned short* __restrict__ fsh, const float* __restrict__ wbuf,
    const int* __restrict__ row_ptr, const int* __restrict__ srcs,
    const float* __restrict__ bias,
    const float* __restrict__ WalN, const float* __restrict__ WredN,
    unsigned short* __restrict__ Ahi,
    float* __restrict__ el_next, float* __restrict__ er_next) {
  __shared__ float red_sm[2][8];
  int n = blockIdx.x;
  int t = threadIdx.x;
  int w = t >> 6, lane = t & 63;
  int half = lane >> 5, lam = lane & 31;
  int head = w*2 + half;
  int k0 = head*DDIM + lam*8;
  if (n >= NNODES) {
    uint4 z = {0,0,0,0};
    *(uint4*)&Ahi[(size_t)n*MCOLS + k0] = z;
    return;
  }
  int beg = row_ptr[n], end = row_ptr[n+1];
  float den = 0.f;
  float ac[8];
  #pragma unroll
  for (int j = 0; j < 8; ++j) ac[j] = 0.f;
  const char* fbyte = (const char*)fsh;
  const unsigned tb = (unsigned)(k0*2);

  int nfull = (end - beg) & ~7;
  int gend = beg + nfull;
  int i = beg;
  int s[8];
  if (i < gend) {
    #pragma unroll
    for (int j = 0; j < 8; ++j) s[j] = srcs[i + j];
  }
  while (i < gend) {
    float wg[8];
    #pragma unroll
    for (int j = 0; j < 8; ++j) {
      float2 wv = *(const float2*)&wbuf[(size_t)(i + j)*HEADS + w*2];
      wg[j] = half ? wv.y : wv.x;
    }
    uint4 u[8];
    #pragma unroll
    for (int j = 0; j < 8; ++j)
      u[j] = *(const uint4*)(fbyte + ((unsigned)s[j]*2048u + tb));
    i += 8;
    if (i < gend) {
      #pragma unroll
      for (int j = 0; j < 8; ++j) s[j] = srcs[i + j];
    }
    #pragma unroll
    for (int j = 0; j < 8; ++j) {
      den += wg[j];
      ac[0] = fmaf(wg[j], blo(u[j].x), ac[0]);
      ac[1] = fmaf(wg[j], bhi(u[j].x), ac[1]);
      ac[2] = fmaf(wg[j], blo(u[j].y), ac[2]);
      ac[3] = fmaf(wg[j], bhi(u[j].y), ac[3]);
      ac[4] = fmaf(wg[j], blo(u[j].z), ac[4]);
      ac[5] = fmaf(wg[j], bhi(u[j].z), ac[5]);
      ac[6] = fmaf(wg[j], blo(u[j].w), ac[6]);
      ac[7] = fmaf(wg[j], bhi(u[j].w), ac[7]);
    }
  }
  for (; i < end; ++i) {
    int sr = srcs[i];
    float2 wv = *(const float2*)&wbuf[(size_t)i*HEADS + w*2];
    float wgt = half ? wv.y : wv.x;
    const uint4 u = *(const uint4*)(fbyte + ((unsigned)sr*2048u + tb));
    den += wgt;
    ac[0] = fmaf(wgt, blo(u.x), ac[0]);
    ac[1] = fmaf(wgt, bhi(u.x), ac[1]);
    ac[2] = fmaf(wgt, blo(u.y), ac[2]);
    ac[3] = fmaf(wgt, bhi(u.y), ac[3]);
    ac[4] = fmaf(wgt, blo(u.z), ac[4]);
    ac[5] = fmaf(wgt, bhi(u.z), ac[5]);
    ac[6] = fmaf(wgt, blo(u.w), ac[6]);
    ac[7] = fmaf(wgt, bhi(u.w), ac[7]);
  }
  float inv = den > 0.f ? 1.f/den : 0.f;
  const float4 bv0 = *(const float4*)&bias[k0];
  const float4 bv1 = *(const float4*)&bias[k0 + 4];
  float o[8];
  o[0] = fmaxf(ac[0]*inv + bv0.x, 0.f);
  o[1] = fmaxf(ac[1]*inv + bv0.y, 0.f);
  o[2] = fmaxf(ac[2]*inv + bv0.z, 0.f);
  o[3] = fmaxf(ac[3]*inv + bv0.w, 0.f);
  o[4] = fmaxf(ac[4]*inv + bv1.x, 0.f);
  o[5] = fmaxf(ac[5]*inv + bv1.y, 0.f);
  o[6] = fmaxf(ac[6]*inv + bv1.z, 0.f);
  o[7] = fmaxf(ac[7]*inv + bv1.w, 0.f);
  uint4 hp;
  hp.x = (unsigned)f2bf(o[0]) | ((unsigned)f2bf(o[1]) << 16);
  hp.y = (unsigned)f2bf(o[2]) | ((unsigned)f2bf(o[3]) << 16);
  hp.z = (unsigned)f2bf(o[4]) | ((unsigned)f2bf(o[5]) << 16);
  hp.w = (unsigned)f2bf(o[6]) | ((unsigned)f2bf(o[7]) << 16);
  *(uint4*)&Ahi[(size_t)n*MCOLS + k0] = hp;
  // el/er next
  float p[8];
  #pragma unroll
  for (int j = 0; j < 8; ++j) p[j] = 0.f;
  #pragma unroll
  for (int j = 0; j < 8; ++j) {
    const float4 wa = *(const float4*)&WalN[(k0+j)*HEADS];
    const float4 wr = *(const float4*)&WredN[(k0+j)*HEADS];
    p[0] = fmaf(o[j], wa.x, p[0]);
    p[1] = fmaf(o[j], wa.y, p[1]);
    p[2] = fmaf(o[j], wa.z, p[2]);
    p[3] = fmaf(o[j], wa.w, p[3]);
    p[4] = fmaf(o[j], wr.x, p[4]);
    p[5] = fmaf(o[j], wr.y, p[5]);
    p[6] = fmaf(o[j], wr.z, p[6]);
    p[7] = fmaf(o[j], wr.w, p[7]);
  }
  for (int off = 32; off; off >>= 1)
    #pragma unroll
    for (int j = 0; j < 8; ++j) p[j] += __shfl_xor(p[j], off);
  if (lane == 0)
    #pragma unroll
    for (int j = 0; j < 8; ++j) red_sm[w][j] = p[j];
  __syncthreads();
  if (t < 8) {
    float v = red_sm[0][t] + red_sm[1][t];
    if (t < 4) el_next[n*HEADS + t] = v;
    else       er_next[n*HEADS + (t-4)] = v;
  }
}

// ---------------- final aggregation (layer 2): flat 8-deep pipeline ----------
__global__ __launch_bounds__(128) void k_agg_out(
    const unsigned short* __restrict__ fsh, const float* __restrict__ wbuf,
    const int* __restrict__ row_ptr, const int* __restrict__ srcs,
    const float* __restrict__ bias, float* __restrict__ out) {
  __shared__ float sm[HEADS*DDIM];
  int n = blockIdx.x;
  int t = threadIdx.x;
  int w = t >> 6, lane = t & 63;
  int half = lane >> 5, lam = lane & 31;
  int head = w*2 + half;
  int k0 = head*DDIM + lam*8;
  int beg = row_ptr[n], end = row_ptr[n+1];
  float den = 0.f;
  float ac[8];
  #pragma unroll
  for (int j = 0; j < 8; ++j) ac[j] = 0.f;
  const char* fbyte = (const char*)fsh;
  const unsigned tb = (unsigned)(k0*2);

  int nfull = (end - beg) & ~7;
  int gend = beg + nfull;
  int i = beg;
  int s[8];
  if (i < gend) {
    #pragma unroll
    for (int j = 0; j < 8; ++j) s[j] = srcs[i + j];
  }
  while (i < gend) {
    float wg[8];
    #pragma unroll
    for (int j = 0; j < 8; ++j) {
      float2 wv = *(const float2*)&wbuf[(size_t)(i + j)*HEADS + w*2];
      wg[j] = half ? wv.y : wv.x;
    }
    uint4 u[8];
    #pragma unroll
    for (int j = 0; j < 8; ++j)
      u[j] = *(const uint4*)(fbyte + ((unsigned)s[j]*2048u + tb));
    i += 8;
    if (i < gend) {
      #pragma unroll
      for (int j = 0; j < 8; ++j) s[j] = srcs[i + j];
    }
    #pragma unroll
    for (int j = 0; j < 8; ++j) {
      den += wg[j];
      ac[0] = fmaf(wg[j], blo(u[j].x), ac[0]);
      ac[1] = fmaf(wg[j], bhi(u[j].x), ac[1]);
      ac[2] = fmaf(wg[j], blo(u[j].y), ac[2]);
      ac[3] = fmaf(wg[j], bhi(u[j].y), ac[3]);
      ac[4] = fmaf(wg[j], blo(u[j].z), ac[4]);
      ac[5] = fmaf(wg[j], bhi(u[j].z), ac[5]);
      ac[6] = fmaf(wg[j], blo(u[j].w), ac[6]);
      ac[7] = fmaf(wg[j], bhi(u[j].w), ac[7]);
    }
  }
  for (; i < end; ++i) {
    int sr = srcs[i];
    float2 wv = *(const float2*)&wbuf[(size_t)i*HEADS + w*2];
    float wgt = half ? wv.y : wv.x;
    const uint4 u = *(const uint4*)(fbyte + ((unsigned)sr*2048u + tb));
    den += wgt;
    ac[0] = fmaf(wgt, blo(u.x), ac[0]);
    ac[1] = fmaf(wgt, bhi(u.x), ac[1]);
    ac[2] = fmaf(wgt, blo(u.y), ac[2]);
    ac[3] = fmaf(wgt, bhi(u.y), ac[3]);
    ac[4] = fmaf(wgt, blo(u.z), ac[4]);
    ac[5] = fmaf(wgt, bhi(u.z), ac[5]);
    ac[6] = fmaf(wgt, blo(u.w), ac[6]);
    ac[7] = fmaf(wgt, bhi(u.w), ac[7]);
  }
  float inv = den > 0.f ? 1.f/den : 0.f;
  const float4 bv0 = *(const float4*)&bias[k0];
  const float4 bv1 = *(const float4*)&bias[k0 + 4];
  sm[k0+0] = ac[0]*inv + bv0.x;
  sm[k0+1] = ac[1]*inv + bv0.y;
  sm[k0+2] = ac[2]*inv + bv0.z;
  sm[k0+3] = ac[3]*inv + bv0.w;
  sm[k0+4] = ac[4]*inv + bv1.x;
  sm[k0+5] = ac[5]*inv + bv1.y;
  sm[k0+6] = ac[6]*inv + bv1.z;
  sm[k0+7] = ac[7]*inv + bv1.w;
  __syncthreads();
  #pragma unroll
  for (int rep = 0; rep < 2; ++rep) {
    int d = t + rep*128;
    out[(size_t)n*DDIM + d] =
        0.25f*((sm[d] + sm[DDIM + d]) + (sm[2*DDIM + d] + sm[3*DDIM + d]));
  }
}

extern "C" void kernel_launch(void* const* d_in, const int* in_sizes, int n_in,
                              void* d_out, int out_size, void* d_ws, size_t ws_size,
                              hipStream_t stream) {
  const float* x   = (const float*)d_in[0];
  const int*   src = (const int*)d_in[1];
  const int*   dst = (const int*)d_in[2];
  const float* Wsrc[3] = {(const float*)d_in[3], (const float*)d_in[8],  (const float*)d_in[13]};
  const float* Wdst[3] = {(const float*)d_in[4], (const float*)d_in[9],  (const float*)d_in[14]};
  const float* al[3]   = {(const float*)d_in[5], (const float*)d_in[10], (const float*)d_in[15]};
  const float* ar[3]   = {(const float*)d_in[6], (const float*)d_in[11], (const float*)d_in[16]};
  const float* bb[3]   = {(const float*)d_in[7], (const float*)d_in[12], (const float*)d_in[17]};

  char* ws = (char*)d_ws;
  size_t off = 0;
  auto alloc = [&](size_t bytes) { void* p = ws + off; off += (bytes + 255) & ~255ull; return p; };
  unsigned short* xh   = (unsigned short*)alloc((size_t)NPAD*512*2);    // x bf16
  unsigned short* gbuf = (unsigned short*)alloc((size_t)NPAD*2048*2);   // g0 [N][H*512]
  unsigned short* hbuf = (unsigned short*)alloc((size_t)NPAD*MCOLS*2);  // h1 / h2
  unsigned short* fshB = (unsigned short*)alloc((size_t)NPAD*MCOLS*2);  // fs1 / fs2
  unsigned short* Th0  = (unsigned short*)alloc((size_t)1024*512*2);
  unsigned short* Th1  = (unsigned short*)alloc((size_t)1024*1024*2);
  unsigned short* Th2  = (unsigned short*)alloc((size_t)1024*1024*2);
  float* elA  = (float*)alloc((size_t)NNODES*HEADS*4);
  float* elB  = (float*)alloc((size_t)NNODES*HEADS*4);
  float* erA  = (float*)alloc((size_t)NNODES*HEADS*4);
  float* erB  = (float*)alloc((size_t)NNODES*HEADS*4);
  float* wbuf = (float*)alloc((size_t)NEDGES*HEADS*4);
  float* WredB[3]; float* WalB[3];
  for (int l = 0; l < 3; ++l) {
    WredB[l] = (float*)alloc(1024*HEADS*4);
    WalB[l]  = (float*)alloc(1024*HEADS*4);
  }
  int* deg     = (int*)alloc((size_t)NNODES*4);
  int* row_ptr = (int*)alloc((size_t)(NNODES+1)*4);
  int* cursor  = (int*)alloc((size_t)NNODES*4);
  int* srcs    = (int*)alloc((size_t)NEDGES*4);
  int* dsts    = (int*)alloc((size_t)NEDGES*4);
  (void)ws_size; (void)in_sizes; (void)n_in; (void)out_size;

  // CSR build
  hipMemsetAsync(deg, 0, (size_t)NNODES*4, stream);
  k_hist<<<(NEDGES+255)/256, 256, 0, stream>>>(dst, deg, NEDGES);
  k_scan<<<1, 1024, 0, stream>>>(deg, row_ptr, cursor);
  k_fill<<<(NEDGES+255)/256, 256, 0, stream>>>(src, dst, cursor, srcs, dsts, NEDGES);

  // folds + all three W transposes in one launch
  k_fold_cvt_all<<<5120 + 512 + 1024 + 1024, 256, 0, stream>>>(
      Wdst[0], ar[0], WredB[0], Wsrc[0], al[0], WalB[0],
      Wdst[1], ar[1], WredB[1], Wsrc[1], al[1], WalB[1],
      Wdst[2], ar[2], WredB[2], Wsrc[2], al[2], WalB[2],
      Th0, Th1, Th2);

  // x -> bf16 table + el0/er0
  k_prep0<<<NPAD, 256, 0, stream>>>(x, WalB[0], WredB[0], xh, elA, erA);

  const int WGT_GRID = (NEDGES + 255)/256;

  // ---- layer 0: wgt -> per-head agg(x) -> block-diagonal GEMM -> h1 ----
  k_wgt_e<<<WGT_GRID, 256, 0, stream>>>(elA, erA, srcs, dsts, wbuf, NEDGES);
  k_agg5<<<NPAD/2, 128, 0, stream>>>(xh, wbuf, row_ptr, srcs, gbuf);
  k_gemm<1, 1><<<NBM*8, 256, 0, stream>>>(gbuf, Th0, bb[0], hbuf, 512, 2048);
  k_elr<<<NNODES, 256, 0, stream>>>(hbuf, WalB[1], WredB[1], elB, erB);

  // ---- layer 1: wgt -> GEMM(h1) -> fs1 -> agg (+el2/er2) -> h2 ----
  k_wgt_e<<<WGT_GRID, 256, 0, stream>>>(elB, erB, srcs, dsts, wbuf, NEDGES);
  k_gemm<0, 0><<<NBM*8, 256, 0, stream>>>(hbuf, Th1, nullptr, fshB, 1024, 1024);
  k_agg_f<<<NPAD, 128, 0, stream>>>(fshB, wbuf, row_ptr, srcs, bb[1],
                                    WalB[2], WredB[2], hbuf, elA, erA);

  // ---- layer 2: wgt -> GEMM(h2) -> fs2 -> agg_out (head mean) -> out ----
  k_wgt_e<<<WGT_GRID, 256, 0, stream>>>(elA, erA, srcs, dsts, wbuf, NEDGES);
  k_gemm<0, 0><<<NBM*8, 256, 0, stream>>>(hbuf, Th2, nullptr, fshB, 1024, 1024);
  k_agg_out<<<NNODES, 128, 0, stream>>>(fshB, wbuf, row_ptr, srcs, bb[2],
                                        (float*)d_out);
}